// Round 11
// baseline (148.438 us; speedup 1.0000x reference)
//
#include <hip/hip_runtime.h>
#include <math.h>

#define BATCH 16
#define LEN   160000
#define NFFT  512
#define HOP   128
#define NT    1251      // 1 + (160000+512-512)/128
#define NF    257
#define PADC  256
#define TWO_PI 6.28318530717958647692f
// float2-LDS padded index: +1 float2 per 16 -> conflict-free b64 patterns
#define P2(i) ((i) + ((i) >> 4))
#define FB2  544        // padded 512-float2 FFT region (P2(511)=542 < 544)
#define RSTR 272        // staging row stride in float2: 2 rows == FB2 exactly
#define GSTR 264        // floor kernel LDS row stride (floats)

__device__ __forceinline__ int reflect_idx(int j) {
    j = j < 0 ? -j : j;
    j = j >= LEN ? 2*LEN - 2 - j : j;
    return j;
}

__device__ __forceinline__ float hann(int n) {
    return 0.5f - 0.5f * __cosf(TWO_PI * (float)n * (1.0f / 512.0f));
}

__device__ __forceinline__ void cmul(float& dr, float& di, float ar, float ai,
                                     float br, float bi) {
    dr = ar*br - ai*bi; di = ar*bi + ai*br;
}

// ---------- sorted-4-smallest tuple machinery (exact, branchless) ----------
struct T4 { float m0, m1, m2, m3; };   // ascending

__device__ __forceinline__ void ins(T4& a, float v) {
    const float x0 = fminf(a.m0, v);  const float c0 = fmaxf(a.m0, v);
    const float x1 = fminf(a.m1, c0); const float c1 = fmaxf(a.m1, c0);
    const float x2 = fminf(a.m2, c1); const float c2 = fmaxf(a.m2, c1);
    const float x3 = fminf(a.m3, c2);
    a.m0 = x0; a.m1 = x1; a.m2 = x2; a.m3 = x3;
}

__device__ __forceinline__ T4 merge4(const T4& a, const T4& b) {
    const float l0 = fminf(a.m0, b.m3);
    const float l1 = fminf(a.m1, b.m2);
    const float l2 = fminf(a.m2, b.m1);
    const float l3 = fminf(a.m3, b.m0);
    const float t0 = fminf(l0, l2), t2 = fmaxf(l0, l2);
    const float t1 = fminf(l1, l3), t3 = fmaxf(l1, l3);
    T4 r;
    r.m0 = fminf(t0, t1); r.m1 = fmaxf(t0, t1);
    r.m2 = fminf(t2, t3); r.m3 = fmaxf(t2, t3);
    return r;
}

__device__ __forceinline__ T4 sort4(float a, float b, float c, float d) {
    const float x0 = fminf(a, b), x1 = fmaxf(a, b);
    const float x2 = fminf(c, d), x3 = fmaxf(c, d);
    const float y0 = fminf(x0, x2), y2 = fmaxf(x0, x2);
    const float y1 = fminf(x1, x3), y3 = fmaxf(x1, x3);
    T4 r; r.m0 = y0; r.m1 = fminf(y1, y2); r.m2 = fmaxf(y1, y2); r.m3 = y3;
    return r;
}

// 8-point DFT in registers. y[m] = sum_r v[r] * exp(sign*2*pi*i*r*m/8).
__device__ __forceinline__ void dft8(float vr[8], float vi[8], float sign) {
    const float K = 0.70710678118654752f;
    float ar=vr[0]+vr[4], ai=vi[0]+vi[4];
    float br=vr[0]-vr[4], bi=vi[0]-vi[4];
    float cr=vr[2]+vr[6], ci=vi[2]+vi[6];
    float dr=vr[2]-vr[6], di=vi[2]-vi[6];
    float er=vr[1]+vr[5], ei=vi[1]+vi[5];
    float fr=vr[1]-vr[5], fi=vi[1]-vi[5];
    float gr=vr[3]+vr[7], gi=vi[3]+vi[7];
    float hr=vr[3]-vr[7], hi=vi[3]-vi[7];
    const float W4dr = -sign*di, W4di = sign*dr;
    const float W4hr = -sign*hi, W4hi = sign*hr;
    const float E0r=ar+cr, E0i=ai+ci, E2r=ar-cr, E2i=ai-ci;
    const float E1r=br+W4dr, E1i=bi+W4di, E3r=br-W4dr, E3i=bi-W4di;
    const float O0r=er+gr, O0i=ei+gi, O2r=er-gr, O2i=ei-gi;
    const float O1r=fr+W4hr, O1i=fi+W4hi, O3r=fr-W4hr, O3i=fi-W4hi;
    const float T1r = K*(O1r - sign*O1i), T1i = K*(O1i + sign*O1r);
    const float T2r = -sign*O2i,          T2i = sign*O2r;
    const float T3r = K*(-O3r - sign*O3i), T3i = K*(-O3i + sign*O3r);
    vr[0]=E0r+O0r; vi[0]=E0i+O0i;  vr[4]=E0r-O0r; vi[4]=E0i-O0i;
    vr[1]=E1r+T1r; vi[1]=E1i+T1i;  vr[5]=E1r-T1r; vi[5]=E1i-T1i;
    vr[2]=E2r+T2r; vi[2]=E2i+T2i;  vr[6]=E2r-T2r; vi[6]=E2i-T2i;
    vr[3]=E3r+T3r; vi[3]=E3i+T3i;  vr[7]=E3r-T3r; vi[7]=E3i-T3i;
}

// Twiddle powers w^1..w^7 from th, log-depth (2-3 dependent cmuls).
__device__ __forceinline__ void twiddles(float th, float wr[8], float wi[8]) {
    wr[0] = 1.0f; wi[0] = 0.0f;
    __sincosf(th, &wi[1], &wr[1]);
    cmul(wr[2], wi[2], wr[1], wi[1], wr[1], wi[1]);
    cmul(wr[3], wi[3], wr[2], wi[2], wr[1], wi[1]);
    cmul(wr[4], wi[4], wr[2], wi[2], wr[2], wi[2]);
    cmul(wr[5], wi[5], wr[3], wi[3], wr[2], wi[2]);
    cmul(wr[6], wi[6], wr[3], wi[3], wr[3], wi[3]);
    cmul(wr[7], wi[7], wr[4], wi[4], wr[3], wi[3]);
}

// One Stockham radix-8 pass, IN PLACE on an interleaved float2 region,
// one wave = one FFT (j in 0..63). Barrier-free: all 8 ds_read_b64
// precede all 8 ds_write_b64 in program order (single-wave DS ordering).
template<int NS>
__device__ __forceinline__ void fft_pass2(float2* S, int j, float sign) {
    float vr[8], vi[8];
    #pragma unroll
    for (int r = 0; r < 8; ++r) { const float2 v = S[P2(j + 64*r)]; vr[r] = v.x; vi[r] = v.y; }
    const float th = sign * (TWO_PI / (8.0f * (float)NS)) * (float)(j & (NS - 1));
    float wr[8], wi[8];
    twiddles(th, wr, wi);
    #pragma unroll
    for (int r = 1; r < 8; ++r) {
        const float tr = vr[r]*wr[r] - vi[r]*wi[r];
        vi[r] = vr[r]*wi[r] + vi[r]*wr[r]; vr[r] = tr;
    }
    dft8(vr, vi, sign);
    const int base = ((j / NS) * (8 * NS)) + (j & (NS - 1));
    #pragma unroll
    for (int r = 0; r < 8; ++r) S[P2(base + r*NS)] = make_float2(vr[r], vi[r]);
}

// Final pass (NS=64): results stay in REGISTERS; lane j holds y[j+64r].
__device__ __forceinline__ void fft_pass_last2(const float2* S, int j, float sign,
                                               float vr[8], float vi[8]) {
    #pragma unroll
    for (int r = 0; r < 8; ++r) { const float2 v = S[P2(j + 64*r)]; vr[r] = v.x; vi[r] = v.y; }
    const float th = sign * (TWO_PI / 512.0f) * (float)j;
    float wr[8], wi[8];
    twiddles(th, wr, wi);
    #pragma unroll
    for (int r = 1; r < 8; ++r) {
        const float tr = vr[r]*wr[r] - vi[r]*wi[r];
        vi[r] = vr[r]*wi[r] + vi[r]*wr[r]; vr[r] = tr;
    }
    dft8(vr, vi, sign);
}

// K1: STFT of BOTH signals via one complex FFT per frame: z = enh + i*noi.
// 4 frames per block (one per wave), wave-autonomous in-place radix-8
// Stockham on interleaved float2 LDS (b64 DS ops), ZERO __syncthreads.
// Last pass in registers; Hermitian partner via __shfl.
__global__ __launch_bounds__(256, 6) void stft_kernel(const float* __restrict__ enh,
                                                      const float* __restrict__ noi,
                                                      float2* __restrict__ e_spec,
                                                      float*  __restrict__ n_mag) {
    __shared__ float2 A[4*FB2];   // 17408 B
    const int tid = threadIdx.x;
    const int w = tid >> 6, j = tid & 63;
    const int tr_ = blockIdx.x * 4 + w;
    const bool live = tr_ < NT;
    const int t = live ? tr_ : NT - 1;
    const int b = blockIdx.y;
    float2* a = A + w*FB2;

    // pass 0: global -> registers (windowed), dft8, write A
    {
        const int sbase = t * HOP - PADC;
        float vr[8], vi[8];
        if (sbase >= 0 && sbase + NFFT <= LEN) {
            const float* __restrict__ pe = enh + b * LEN + sbase;
            const float* __restrict__ pn = noi + b * LEN + sbase;
            #pragma unroll
            for (int r = 0; r < 8; ++r) {
                const int n = j + 64*r;
                const float wd = hann(n);
                vr[r] = pe[n] * wd;
                vi[r] = pn[n] * wd;
            }
        } else {
            const float* __restrict__ pe = enh + b * LEN;
            const float* __restrict__ pn = noi + b * LEN;
            #pragma unroll
            for (int r = 0; r < 8; ++r) {
                const int n = j + 64*r;
                const int idx = reflect_idx(sbase + n);
                const float wd = hann(n);
                vr[r] = pe[idx] * wd;
                vi[r] = pn[idx] * wd;
            }
        }
        dft8(vr, vi, -1.0f);
        #pragma unroll
        for (int r = 0; r < 8; ++r) a[P2(8*j + r)] = make_float2(vr[r], vi[r]);
    }
    fft_pass2<8>(a, j, -1.0f);
    float zr[8], zi[8];
    fft_pass_last2(a, j, -1.0f, zr, zi);

    // Hermitian partner via cross-lane shuffle (regs 4..7 of lane (64-j)&63)
    const int src = (64 - j) & 63;
    float pr[4], pi_[4];
    #pragma unroll
    for (int q = 4; q < 8; ++q) {
        pr[q-4]  = __shfl(zr[q], src);
        pi_[q-4] = __shfl(zi[q], src);
    }
    if (live) {
        const int obase = (b * NT + t) * NF;
        #pragma unroll
        for (int r = 0; r < 4; ++r) {
            const int kk = j + 64*r;
            const float yr = (j == 0) ? zr[(8 - r) & 7] : pr[3 - r];
            const float yi = (j == 0) ? zi[(8 - r) & 7] : pi_[3 - r];
            const float er = 0.5f*(zr[r] + yr), ei = 0.5f*(zi[r] - yi);
            const float nr = 0.5f*(zi[r] + yi), ni = 0.5f*(yr - zr[r]);
            e_spec[obase + kk] = make_float2(er, ei);
            n_mag[obase + kk] = fmaxf(sqrtf(nr*nr + ni*ni), 1e-6f);
        }
        if (j == 0) {   // kk = 256: self-conjugate bin
            e_spec[obase + 256] = make_float2(zr[4], 0.0f);
            n_mag[obase + 256] = fmaxf(fabsf(zi[4]), 1e-6f);
        }
    }
}

// K2: FULLY fused floor. Tile = 16 outputs (24 quantile rows incl. +/-4
// halo; 54-element time window in registers). Quantile = 4th-smallest of
// 31 via chunked selection. Freq-pool k=5 via LDS; time-pool k=9 sliding.
__global__ __launch_bounds__(256) void floor_kernel(const float* __restrict__ n_mag,
                                                    float* __restrict__ floor_) {
    __shared__ float q[24][GSTR];
    __shared__ float fq[24];
    const int tid = threadIdx.x;
    const int t0 = blockIdx.x * 16, b = blockIdx.y;
    const float* __restrict__ pb = n_mag + b * NT * NF;

    // ---- phase A: quantile rows k=0..23 (tq = t0-4+k) for f = tid ----
    {
        float wv[54];
        #pragma unroll
        for (int r = 0; r < 54; ++r) {
            int tr = t0 - 19 + r;
            tr = tr < 0 ? 0 : (tr > NT - 1 ? NT - 1 : tr);
            wv[r] = pb[tr * NF + tid];
        }
        T4 ch[6];
        #pragma unroll
        for (int c = 0; c < 6; ++c)
            ch[c] = merge4(sort4(wv[8*c],   wv[8*c+1], wv[8*c+2], wv[8*c+3]),
                           sort4(wv[8*c+4], wv[8*c+5], wv[8*c+6], wv[8*c+7]));
        #pragma unroll
        for (int k = 0; k < 24; ++k) {
            const int c0 = (k + 7) >> 3;      // full chunks c0, c0+1, c0+2
            T4 m = merge4(merge4(ch[c0], ch[c0+1]), ch[c0+2]);
            #pragma unroll
            for (int jj = k; jj < 8*c0; ++jj) ins(m, wv[jj]);        // head
            #pragma unroll
            for (int jj = 8*c0 + 24; jj < k + 31; ++jj) ins(m, wv[jj]); // tail
            q[k][tid] = m.m3;
        }
    }
    // f = 256 column: threads 0..23, one quantile row each (naive 31-insert)
    if (tid < 24) {
        const int k = tid;
        T4 m; m.m0 = m.m1 = m.m2 = m.m3 = 3.4e38f;
        for (int dt = -15; dt <= 15; ++dt) {
            int tt = t0 - 4 + k + dt;
            tt = tt < 0 ? 0 : (tt > NT - 1 ? NT - 1 : tt);
            ins(m, pb[tt * NF + 256]);
        }
        q[k][256] = m.m3;
    }
    __syncthreads();

    // ---- phase B: freq pool k=5 (zero-pad) into registers ----
    float fp[24];
    {
        const int f = tid;
        #pragma unroll
        for (int k = 0; k < 24; ++k) {
            float acc = 0.0f;
            #pragma unroll
            for (int df = -2; df <= 2; ++df) {
                const int ff = f + df;
                if (ff >= 0 && ff < NF) acc += q[k][ff];
            }
            fp[k] = acc * (1.0f / 5.0f);
        }
    }
    if (tid < 24) {   // f = 256 pooled rows -> fq
        const int k = tid;
        fq[k] = (q[k][254] + q[k][255] + q[k][256]) * (1.0f / 5.0f);
    }
    __syncthreads();

    // ---- phase C: zero out-of-range rows, time pool k=9 sliding, store ----
    {
        const int f = tid;
        #pragma unroll
        for (int k = 0; k < 24; ++k) {
            const int tq = t0 - 4 + k;
            fp[k] = (tq >= 0 && tq < NT) ? fp[k] : 0.0f;
        }
        float acc = 0.0f;
        #pragma unroll
        for (int k = 0; k < 9; ++k) acc += fp[k];
        #pragma unroll
        for (int to = 0; to < 16; ++to) {
            const int t = t0 + to;
            if (t < NT)
                floor_[(b * NT + t) * NF + f] = fmaxf(acc * (1.0f / 9.0f), 1e-6f);
            if (to < 15) acc += fp[to + 9] - fp[to];
        }
    }
    if (tid < 16) {   // f = 256 outputs
        const int to = tid;
        const int t = t0 + to;
        if (t < NT) {
            float acc = 0.0f;
            #pragma unroll
            for (int k = 0; k < 9; ++k) {
                const int tq = t0 - 4 + to + k;
                acc += (tq >= 0 && tq < NT) ? fq[to + k] : 0.0f;
            }
            floor_[(b * NT + t) * NF + 256] = fmaxf(acc * (1.0f / 9.0f), 1e-6f);
        }
    }
}

// K3: fused [mask + ISTFT + OLA]. Block = 256 threads / 4 waves computes
// frames t0..t0+7 EXACTLY ONCE (wave-local packed IFFTs on float2 LDS,
// zero halo), windows them in place, one barrier, then overlap-adds:
// fully-covered samples -> plain store; boundary samples -> atomicAdd of
// the pre-normalized partial (out zeroed by hipMemsetAsync).
__global__ __launch_bounds__(256, 6) void istft_ola_kernel(const float2* __restrict__ g,
                                                           const float* __restrict__ floor_,
                                                           float* __restrict__ out) {
    __shared__ float2 G[8*RSTR];   // 8 rows x 272 float2 = 17408 B
    const int tid = threadIdx.x;
    const int w = tid >> 6, j = tid & 63;
    const int t0 = blockIdx.x * 8, b = blockIdx.y;
    const int ta = t0 + 2*w;

    float2* g0 = G + (2*w) * RSTR;
    float2* g1 = g0 + RSTR;

    // mask phase (wave-local): fill this wave's 2 staging rows
    for (int e = j; e < 2 * NF; e += 64) {
        const int h = (e >= NF) ? 1 : 0;
        const int kk = e - h * NF;
        const int t = ta + h;
        float grv = 0.0f, giv = 0.0f;
        if (t < NT) {
            const int idx = (b * NT + t) * NF + kk;
            const float fl = floor_[idx];
            const float2 e2 = g[idx];
            const float a = sqrtf(e2.x * e2.x + e2.y * e2.y);
            const float emag = fmaxf(a, 1e-6f);
            const float xarg = (emag - 1.5f * fl) / (0.15f * fl + 1e-6f);
            const float mask = 1.0f / (1.0f + __expf(-xarg));
            const float fm = 0.08f + 0.92f * (0.65f + 0.35f * mask);
            const float scale = emag * fm / fmaxf(a, 1e-12f);
            grv = e2.x * scale; giv = e2.y * scale;
        }
        (h ? g1 : g0)[kk] = make_float2(grv, giv);
    }

    float2* a = g0;   // FFT region = this wave's two staging rows (2*RSTR == FB2)

    // pass 0: build packed C(n) = G1full + i*G2full from staging, dft8,
    // write back into the same region (all reads precede all writes).
    {
        float vr[8], vi[8];
        #pragma unroll
        for (int r = 0; r < 8; ++r) {
            const int n = j + 64*r;
            float cr, ci;
            if (n <= 256) {
                const float2 v0 = g0[n], v1 = g1[n];
                cr = v0.x - v1.y;
                ci = v0.y + v1.x;
            } else {
                const int m = 512 - n;
                const float2 v0 = g0[m], v1 = g1[m];
                cr = v0.x + v1.y;
                ci = v1.x - v0.y;
            }
            vr[r] = cr; vi[r] = ci;
        }
        dft8(vr, vi, 1.0f);
        #pragma unroll
        for (int r = 0; r < 8; ++r) a[P2(8*j + r)] = make_float2(vr[r], vi[r]);
    }
    fft_pass2<8>(a, j, 1.0f);
    float xr[8], xi[8];
    fft_pass_last2(a, j, 1.0f, xr, xi);

    // window in place: .x plane = frame ta, .y plane = frame ta+1
    #pragma unroll
    for (int r = 0; r < 8; ++r) {
        const int n = j + 64*r;
        const float wd = hann(n) * (1.0f / 512.0f);
        a[P2(n)] = make_float2(xr[r] * wd, xi[r] * wd);
    }
    __syncthreads();

    // OLA: samples i in [t0*128, t0*128 + 1408) (padded coords)
    const int i0 = t0 << 7;
    for (int s = tid; s < 1408; s += 256) {
        const int i = i0 + s;
        const int jj = i - PADC;
        if (jj < 0 || jj >= LEN) continue;
        const int tl = (i >= 384) ? ((i - 384) >> 7) : 0;
        int th = i >> 7; if (th > NT - 1) th = NT - 1;
        const int ca = tl > t0 ? tl : t0;             // this block's frame range
        const int cb = th < t0 + 7 ? th : t0 + 7;
        if (cb < ca) continue;
        float acc = 0.0f;
        for (int t = ca; t <= cb; ++t) {
            const int ft = t - t0;
            const int n = i - (t << 7);
            const float2 v = G[(ft >> 1) * FB2 + P2(n)];
            acc += (ft & 1) ? v.y : v.x;
        }
        float winv;
        if (th - tl == 3) winv = (2.0f / 3.0f);       // COLA: sum hann^2 = 1.5
        else {
            float wacc = 0.0f;
            for (int t = tl; t <= th; ++t) {
                const float wd = hann(i - (t << 7));
                wacc += wd * wd;
            }
            winv = 1.0f / fmaxf(wacc, 1e-11f);
        }
        const float v = acc * winv;
        if (tl >= t0 && th <= t0 + 7) out[b * LEN + jj] = v;        // unique owner
        else atomicAdd(out + b * LEN + jj, v);                      // boundary partial
    }
}

extern "C" void kernel_launch(void* const* d_in, const int* in_sizes, int n_in,
                              void* d_out, int out_size, void* d_ws, size_t ws_size,
                              hipStream_t stream) {
    const float* noisy    = (const float*)d_in[0];
    const float* enhanced = (const float*)d_in[1];
    float* out = (float*)d_out;

    // workspace layout (floats), total 20576448 (~82.3 MB):
    //   e_spec : [0, 10288224)              (16*1251*257 float2)
    //   floor  : [10288224, 15432336)
    //   n_mag  : [15432336, 20576448)
    float* ws = (float*)d_ws;
    float2* e_spec = (float2*)ws;
    float* floor_ = ws + 10288224;
    float* n_mag  = ws + 15432336;

    stft_kernel <<<dim3((NT + 3) / 4, BATCH), dim3(256), 0, stream>>>(enhanced, noisy, e_spec, n_mag);
    floor_kernel<<<dim3((NT + 15) / 16, BATCH), dim3(256), 0, stream>>>(n_mag, floor_);
    hipMemsetAsync(out, 0, (size_t)BATCH * LEN * sizeof(float), stream);
    istft_ola_kernel<<<dim3((NT + 7) / 8, BATCH), dim3(256), 0, stream>>>(e_spec, floor_, out);
}

// Round 12
// 145.019 us; speedup vs baseline: 1.0236x; 1.0236x over previous
//
#include <hip/hip_runtime.h>
#include <math.h>

#define BATCH 16
#define LEN   160000
#define NFFT  512
#define HOP   128
#define NT    1251      // 1 + (160000+512-512)/128
#define NF    257
#define PADC  256
#define TWO_PI 6.28318530717958647692f
// padded LDS index: +1 float per 32 -> breaks power-of-2 bank aliasing
#define P(i) ((i) + ((i) >> 5))
#define FBUF 528        // padded 512-float FFT region (P(511)=526 < 528)
#define GSTR 264        // staging row stride: 2 rows == FBUF exactly

__device__ __forceinline__ int reflect_idx(int j) {
    j = j < 0 ? -j : j;
    j = j >= LEN ? 2*LEN - 2 - j : j;
    return j;
}

__device__ __forceinline__ float hann(int n) {
    return 0.5f - 0.5f * __cosf(TWO_PI * (float)n * (1.0f / 512.0f));
}

// ---------- sorted-4-smallest tuple machinery (exact, branchless) ----------
struct T4 { float m0, m1, m2, m3; };   // ascending

__device__ __forceinline__ void ins(T4& a, float v) {
    const float x0 = fminf(a.m0, v);  const float c0 = fmaxf(a.m0, v);
    const float x1 = fminf(a.m1, c0); const float c1 = fmaxf(a.m1, c0);
    const float x2 = fminf(a.m2, c1); const float c2 = fmaxf(a.m2, c1);
    const float x3 = fminf(a.m3, c2);
    a.m0 = x0; a.m1 = x1; a.m2 = x2; a.m3 = x3;
}

__device__ __forceinline__ T4 merge4(const T4& a, const T4& b) {
    const float l0 = fminf(a.m0, b.m3);
    const float l1 = fminf(a.m1, b.m2);
    const float l2 = fminf(a.m2, b.m1);
    const float l3 = fminf(a.m3, b.m0);
    const float t0 = fminf(l0, l2), t2 = fmaxf(l0, l2);
    const float t1 = fminf(l1, l3), t3 = fmaxf(l1, l3);
    T4 r;
    r.m0 = fminf(t0, t1); r.m1 = fmaxf(t0, t1);
    r.m2 = fminf(t2, t3); r.m3 = fmaxf(t2, t3);
    return r;
}

__device__ __forceinline__ T4 sort4(float a, float b, float c, float d) {
    const float x0 = fminf(a, b), x1 = fmaxf(a, b);
    const float x2 = fminf(c, d), x3 = fmaxf(c, d);
    const float y0 = fminf(x0, x2), y2 = fmaxf(x0, x2);
    const float y1 = fminf(x1, x3), y3 = fmaxf(x1, x3);
    T4 r; r.m0 = y0; r.m1 = fminf(y1, y2); r.m2 = fmaxf(y1, y2); r.m3 = y3;
    return r;
}

// 8-point DFT in registers. y[m] = sum_r v[r] * exp(sign*2*pi*i*r*m/8).
__device__ __forceinline__ void dft8(float vr[8], float vi[8], float sign) {
    const float K = 0.70710678118654752f;
    float ar=vr[0]+vr[4], ai=vi[0]+vi[4];
    float br=vr[0]-vr[4], bi=vi[0]-vi[4];
    float cr=vr[2]+vr[6], ci=vi[2]+vi[6];
    float dr=vr[2]-vr[6], di=vi[2]-vi[6];
    float er=vr[1]+vr[5], ei=vi[1]+vi[5];
    float fr=vr[1]-vr[5], fi=vi[1]-vi[5];
    float gr=vr[3]+vr[7], gi=vi[3]+vi[7];
    float hr=vr[3]-vr[7], hi=vi[3]-vi[7];
    const float W4dr = -sign*di, W4di = sign*dr;
    const float W4hr = -sign*hi, W4hi = sign*hr;
    const float E0r=ar+cr, E0i=ai+ci, E2r=ar-cr, E2i=ai-ci;
    const float E1r=br+W4dr, E1i=bi+W4di, E3r=br-W4dr, E3i=bi-W4di;
    const float O0r=er+gr, O0i=ei+gi, O2r=er-gr, O2i=ei-gi;
    const float O1r=fr+W4hr, O1i=fi+W4hi, O3r=fr-W4hr, O3i=fi-W4hi;
    const float T1r = K*(O1r - sign*O1i), T1i = K*(O1i + sign*O1r);
    const float T2r = -sign*O2i,          T2i = sign*O2r;
    const float T3r = K*(-O3r - sign*O3i), T3i = K*(-O3i + sign*O3r);
    vr[0]=E0r+O0r; vi[0]=E0i+O0i;  vr[4]=E0r-O0r; vi[4]=E0i-O0i;
    vr[1]=E1r+T1r; vi[1]=E1i+T1i;  vr[5]=E1r-T1r; vi[5]=E1i-T1i;
    vr[2]=E2r+T2r; vi[2]=E2i+T2i;  vr[6]=E2r-T2r; vi[6]=E2i-T2i;
    vr[3]=E3r+T3r; vi[3]=E3i+T3i;  vr[7]=E3r-T3r; vi[7]=E3i-T3i;
}

// One Stockham radix-8 pass, IN PLACE, one wave = one FFT (j in 0..63).
// Safe without any barrier: all 8 ds_reads precede all 8 ds_writes in
// program order, and DS ops from one wave are processed in order.
template<int NS>
__device__ __forceinline__ void fft_pass(float* R, float* I, int j, float sign) {
    float vr[8], vi[8];
    #pragma unroll
    for (int r = 0; r < 8; ++r) { vr[r] = R[P(j + 64*r)]; vi[r] = I[P(j + 64*r)]; }
    const float th = sign * (TWO_PI / (8.0f * (float)NS)) * (float)(j & (NS - 1));
    float w1r, w1i; __sincosf(th, &w1i, &w1r);
    float wr = w1r, wi = w1i;
    #pragma unroll
    for (int r = 1; r < 8; ++r) {
        const float tr = vr[r]*wr - vi[r]*wi;
        vi[r] = vr[r]*wi + vi[r]*wr; vr[r] = tr;
        const float nwr = wr*w1r - wi*w1i;
        wi = wr*w1i + wi*w1r; wr = nwr;
    }
    dft8(vr, vi, sign);
    const int base = ((j / NS) * (8 * NS)) + (j & (NS - 1));
    #pragma unroll
    for (int r = 0; r < 8; ++r) { R[P(base + r*NS)] = vr[r]; I[P(base + r*NS)] = vi[r]; }
}

// Final pass (NS=64): results stay in REGISTERS. After this, lane j holds
// y[j + 64r] in vr[r]/vi[r] (base = j when NS=64). No LDS write.
__device__ __forceinline__ void fft_pass_last(const float* R, const float* I, int j,
                                              float sign, float vr[8], float vi[8]) {
    #pragma unroll
    for (int r = 0; r < 8; ++r) { vr[r] = R[P(j + 64*r)]; vi[r] = I[P(j + 64*r)]; }
    const float th = sign * (TWO_PI / 512.0f) * (float)j;
    float w1r, w1i; __sincosf(th, &w1i, &w1r);
    float wr = w1r, wi = w1i;
    #pragma unroll
    for (int r = 1; r < 8; ++r) {
        const float tr = vr[r]*wr - vi[r]*wi;
        vi[r] = vr[r]*wi + vi[r]*wr; vr[r] = tr;
        const float nwr = wr*w1r - wi*w1i;
        wi = wr*w1i + wi*w1r; wr = nwr;
    }
    dft8(vr, vi, sign);
}

// K1: STFT of BOTH signals via one complex FFT per frame: z = enh + i*noi.
// 4 frames per block (one per wave), wave-autonomous in-place radix-8
// Stockham, ZERO __syncthreads. Last pass in registers; Hermitian
// extraction via __shfl (partner Z[512-kk] = lane (64-j)&63, reg 7-r).
__global__ __launch_bounds__(256, 4) void stft_kernel(const float* __restrict__ enh,
                                                      const float* __restrict__ noi,
                                                      float2* __restrict__ e_spec,
                                                      float*  __restrict__ n_mag) {
    __shared__ float Ar[4*FBUF], Ai[4*FBUF];
    const int tid = threadIdx.x;
    const int w = tid >> 6, j = tid & 63;
    const int tr_ = blockIdx.x * 4 + w;
    const bool live = tr_ < NT;
    const int t = live ? tr_ : NT - 1;
    const int b = blockIdx.y;
    float* ar = Ar + w*FBUF; float* ai = Ai + w*FBUF;

    // pass 0: global -> registers (windowed), dft8, write A
    {
        const int sbase = t * HOP - PADC;
        float vr[8], vi[8];
        if (sbase >= 0 && sbase + NFFT <= LEN) {
            const float* __restrict__ pe = enh + b * LEN + sbase;
            const float* __restrict__ pn = noi + b * LEN + sbase;
            #pragma unroll
            for (int r = 0; r < 8; ++r) {
                const int n = j + 64*r;
                const float wd = hann(n);
                vr[r] = pe[n] * wd;
                vi[r] = pn[n] * wd;
            }
        } else {
            const float* __restrict__ pe = enh + b * LEN;
            const float* __restrict__ pn = noi + b * LEN;
            #pragma unroll
            for (int r = 0; r < 8; ++r) {
                const int n = j + 64*r;
                const int idx = reflect_idx(sbase + n);
                const float wd = hann(n);
                vr[r] = pe[idx] * wd;
                vi[r] = pn[idx] * wd;
            }
        }
        dft8(vr, vi, -1.0f);
        #pragma unroll
        for (int r = 0; r < 8; ++r) { ar[P(8*j + r)] = vr[r]; ai[P(8*j + r)] = vi[r]; }
    }
    fft_pass<8>(ar, ai, j, -1.0f);
    float zr[8], zi[8];
    fft_pass_last(ar, ai, j, -1.0f, zr, zi);

    // Hermitian partner via cross-lane shuffle (regs 4..7 of lane (64-j)&63)
    const int src = (64 - j) & 63;
    float pr[4], pi_[4];
    #pragma unroll
    for (int q = 4; q < 8; ++q) {
        pr[q-4]  = __shfl(zr[q], src);
        pi_[q-4] = __shfl(zi[q], src);
    }
    if (live) {
        const int obase = (b * NT + t) * NF;
        #pragma unroll
        for (int r = 0; r < 4; ++r) {
            const int kk = j + 64*r;
            const float yr = (j == 0) ? zr[(8 - r) & 7] : pr[3 - r];
            const float yi = (j == 0) ? zi[(8 - r) & 7] : pi_[3 - r];
            const float er = 0.5f*(zr[r] + yr), ei = 0.5f*(zi[r] - yi);
            const float nr = 0.5f*(zi[r] + yi), ni = 0.5f*(yr - zr[r]);
            e_spec[obase + kk] = make_float2(er, ei);
            n_mag[obase + kk] = fmaxf(sqrtf(nr*nr + ni*ni), 1e-6f);
        }
        if (j == 0) {   // kk = 256: self-conjugate bin
            e_spec[obase + 256] = make_float2(zr[4], 0.0f);
            n_mag[obase + 256] = fmaxf(fabsf(zi[4]), 1e-6f);
        }
    }
}

// K2: FULLY fused floor. Tile = 16 outputs (24 quantile rows incl. +/-4
// halo; 54-element time window in registers). Quantile = 4th-smallest of
// 31 via chunked selection. Freq-pool k=5 via LDS; time-pool k=9 sliding.
// __launch_bounds__(256,3): VGPR cap ~170 so wv[54]+ch[6] stay RESIDENT
// (at default alloc the compiler chose 36 VGPRs and re-loaded head/tail
// elements from global inside the unrolled window loop -> 3x FETCH).
__global__ __launch_bounds__(256, 3) void floor_kernel(const float* __restrict__ n_mag,
                                                       float* __restrict__ floor_) {
    __shared__ float q[24][GSTR];
    __shared__ float fq[24];
    const int tid = threadIdx.x;
    const int t0 = blockIdx.x * 16, b = blockIdx.y;
    const float* __restrict__ pb = n_mag + b * NT * NF;

    // ---- phase A: quantile rows k=0..23 (tq = t0-4+k) for f = tid ----
    {
        float wv[54];
        #pragma unroll
        for (int r = 0; r < 54; ++r) {
            int tr = t0 - 19 + r;
            tr = tr < 0 ? 0 : (tr > NT - 1 ? NT - 1 : tr);
            wv[r] = pb[tr * NF + tid];
        }
        T4 ch[6];
        #pragma unroll
        for (int c = 0; c < 6; ++c)
            ch[c] = merge4(sort4(wv[8*c],   wv[8*c+1], wv[8*c+2], wv[8*c+3]),
                           sort4(wv[8*c+4], wv[8*c+5], wv[8*c+6], wv[8*c+7]));
        #pragma unroll
        for (int k = 0; k < 24; ++k) {
            const int c0 = (k + 7) >> 3;      // full chunks c0, c0+1, c0+2
            T4 m = merge4(merge4(ch[c0], ch[c0+1]), ch[c0+2]);
            #pragma unroll
            for (int jj = k; jj < 8*c0; ++jj) ins(m, wv[jj]);        // head
            #pragma unroll
            for (int jj = 8*c0 + 24; jj < k + 31; ++jj) ins(m, wv[jj]); // tail
            q[k][tid] = m.m3;
        }
    }
    // f = 256 column: threads 0..23, one quantile row each (naive 31-insert)
    if (tid < 24) {
        const int k = tid;
        T4 m; m.m0 = m.m1 = m.m2 = m.m3 = 3.4e38f;
        for (int dt = -15; dt <= 15; ++dt) {
            int tt = t0 - 4 + k + dt;
            tt = tt < 0 ? 0 : (tt > NT - 1 ? NT - 1 : tt);
            ins(m, pb[tt * NF + 256]);
        }
        q[k][256] = m.m3;
    }
    __syncthreads();

    // ---- phase B: freq pool k=5 (zero-pad) into registers ----
    float fp[24];
    {
        const int f = tid;
        #pragma unroll
        for (int k = 0; k < 24; ++k) {
            float acc = 0.0f;
            #pragma unroll
            for (int df = -2; df <= 2; ++df) {
                const int ff = f + df;
                if (ff >= 0 && ff < NF) acc += q[k][ff];
            }
            fp[k] = acc * (1.0f / 5.0f);
        }
    }
    if (tid < 24) {   // f = 256 pooled rows -> fq
        const int k = tid;
        fq[k] = (q[k][254] + q[k][255] + q[k][256]) * (1.0f / 5.0f);
    }
    __syncthreads();

    // ---- phase C: zero out-of-range rows, time pool k=9 sliding, store ----
    {
        const int f = tid;
        #pragma unroll
        for (int k = 0; k < 24; ++k) {
            const int tq = t0 - 4 + k;
            fp[k] = (tq >= 0 && tq < NT) ? fp[k] : 0.0f;
        }
        float acc = 0.0f;
        #pragma unroll
        for (int k = 0; k < 9; ++k) acc += fp[k];
        #pragma unroll
        for (int to = 0; to < 16; ++to) {
            const int t = t0 + to;
            if (t < NT)
                floor_[(b * NT + t) * NF + f] = fmaxf(acc * (1.0f / 9.0f), 1e-6f);
            if (to < 15) acc += fp[to + 9] - fp[to];
        }
    }
    if (tid < 16) {   // f = 256 outputs
        const int to = tid;
        const int t = t0 + to;
        if (t < NT) {
            float acc = 0.0f;
            #pragma unroll
            for (int k = 0; k < 9; ++k) {
                const int tq = t0 - 4 + to + k;
                acc += (tq >= 0 && tq < NT) ? fq[to + k] : 0.0f;
            }
            floor_[(b * NT + t) * NF + 256] = fmaxf(acc * (1.0f / 9.0f), 1e-6f);
        }
    }
}

// K3: fused [mask + ISTFT + OLA]. Block = 256 threads / 4 waves computes
// frames t0..t0+7 EXACTLY ONCE (wave-local packed IFFTs, zero halo),
// windows them into LDS, one barrier, then overlap-adds:
//   - samples fully covered by this block's frames -> plain store
//   - block-boundary samples -> atomicAdd of the pre-normalized partial
// (out is zeroed by hipMemsetAsync; wacc is analytic so partials are
// order-independent). Replaces istft + ola and the 82 MB frames buffer.
__global__ __launch_bounds__(256, 4) void istft_ola_kernel(const float2* __restrict__ g,
                                                           const float* __restrict__ floor_,
                                                           float* __restrict__ out) {
    __shared__ float gr[8*GSTR], gi[8*GSTR];
    const int tid = threadIdx.x;
    const int w = tid >> 6, j = tid & 63;
    const int t0 = blockIdx.x * 8, b = blockIdx.y;
    const int ta = t0 + 2*w, tb = ta + 1;

    float* g0r = gr + (2*w) * GSTR;      float* g0i = gi + (2*w) * GSTR;
    float* g1r = gr + (2*w + 1) * GSTR;  float* g1i = gi + (2*w + 1) * GSTR;

    // mask phase (wave-local): fill this wave's 2 staging rows
    for (int e = j; e < 2 * NF; e += 64) {
        const int h = (e >= NF) ? 1 : 0;
        const int kk = e - h * NF;
        const int t = ta + h;
        float grv = 0.0f, giv = 0.0f;
        if (t < NT) {
            const int idx = (b * NT + t) * NF + kk;
            const float fl = floor_[idx];
            const float2 e2 = g[idx];
            const float a = sqrtf(e2.x * e2.x + e2.y * e2.y);
            const float emag = fmaxf(a, 1e-6f);
            const float xarg = (emag - 1.5f * fl) / (0.15f * fl + 1e-6f);
            const float mask = 1.0f / (1.0f + __expf(-xarg));
            const float fm = 0.08f + 0.92f * (0.65f + 0.35f * mask);
            const float scale = emag * fm / fmaxf(a, 1e-12f);
            grv = e2.x * scale; giv = e2.y * scale;
        }
        gr[(2*w + h) * GSTR + kk] = grv;
        gi[(2*w + h) * GSTR + kk] = giv;
    }

    float* ar = g0r;   // FFT region = this wave's two staging rows (528 floats)
    float* ai = g0i;

    // pass 0: build packed C(n) = G1full + i*G2full from staging, dft8,
    // write back into the same region (all reads precede all writes).
    {
        float vr[8], vi[8];
        #pragma unroll
        for (int r = 0; r < 8; ++r) {
            const int n = j + 64*r;
            float cr, ci;
            if (n <= 256) {
                cr = g0r[n] - g1i[n];
                ci = g0i[n] + g1r[n];
            } else {
                const int m = 512 - n;
                cr = g0r[m] + g1i[m];
                ci = g1r[m] - g0i[m];
            }
            vr[r] = cr; vi[r] = ci;
        }
        dft8(vr, vi, 1.0f);
        #pragma unroll
        for (int r = 0; r < 8; ++r) { ar[P(8*j + r)] = vr[r]; ai[P(8*j + r)] = vi[r]; }
    }
    fft_pass<8>(ar, ai, j, 1.0f);
    float xr[8], xi[8];
    fft_pass_last(ar, ai, j, 1.0f, xr, xi);

    // window in place: Re plane = frame ta, Im plane = frame tb
    #pragma unroll
    for (int r = 0; r < 8; ++r) {
        const int n = j + 64*r;
        const float wd = hann(n) * (1.0f / 512.0f);
        ar[P(n)] = xr[r] * wd;
        ai[P(n)] = xi[r] * wd;
    }
    __syncthreads();

    // OLA: samples i in [t0*128, t0*128 + 1408) (padded coords)
    const int i0 = t0 << 7;
    for (int s = tid; s < 1408; s += 256) {
        const int i = i0 + s;
        const int jj = i - PADC;
        if (jj < 0 || jj >= LEN) continue;
        const int tl = (i >= 384) ? ((i - 384) >> 7) : 0;
        int th = i >> 7; if (th > NT - 1) th = NT - 1;
        const int ca = tl > t0 ? tl : t0;             // this block's frame range
        const int cb = th < t0 + 7 ? th : t0 + 7;
        if (cb < ca) continue;
        float acc = 0.0f;
        for (int t = ca; t <= cb; ++t) {
            const int ft = t - t0;
            const int n = i - (t << 7);
            acc += ((ft & 1) ? gi : gr)[(ft >> 1) * FBUF + P(n)];
        }
        float winv;
        if (th - tl == 3) winv = (2.0f / 3.0f);       // COLA: sum hann^2 = 1.5
        else {
            float wacc = 0.0f;
            for (int t = tl; t <= th; ++t) {
                const float wd = hann(i - (t << 7));
                wacc += wd * wd;
            }
            winv = 1.0f / fmaxf(wacc, 1e-11f);
        }
        const float v = acc * winv;
        if (tl >= t0 && th <= t0 + 7) out[b * LEN + jj] = v;        // unique owner
        else atomicAdd(out + b * LEN + jj, v);                      // boundary partial
    }
}

extern "C" void kernel_launch(void* const* d_in, const int* in_sizes, int n_in,
                              void* d_out, int out_size, void* d_ws, size_t ws_size,
                              hipStream_t stream) {
    const float* noisy    = (const float*)d_in[0];
    const float* enhanced = (const float*)d_in[1];
    float* out = (float*)d_out;

    // workspace layout (floats), total 20576448 (~82.3 MB):
    //   e_spec : [0, 10288224)              (16*1251*257 float2)
    //   floor  : [10288224, 15432336)
    //   n_mag  : [15432336, 20576448)
    float* ws = (float*)d_ws;
    float2* e_spec = (float2*)ws;
    float* floor_ = ws + 10288224;
    float* n_mag  = ws + 15432336;

    stft_kernel <<<dim3((NT + 3) / 4, BATCH), dim3(256), 0, stream>>>(enhanced, noisy, e_spec, n_mag);
    floor_kernel<<<dim3((NT + 15) / 16, BATCH), dim3(256), 0, stream>>>(n_mag, floor_);
    hipMemsetAsync(out, 0, (size_t)BATCH * LEN * sizeof(float), stream);
    istft_ola_kernel<<<dim3((NT + 7) / 8, BATCH), dim3(256), 0, stream>>>(e_spec, floor_, out);
}

// Round 13
// 142.811 us; speedup vs baseline: 1.0394x; 1.0155x over previous
//
#include <hip/hip_runtime.h>
#include <math.h>

#define BATCH 16
#define LEN   160000
#define NFFT  512
#define HOP   128
#define NT    1251      // 1 + (160000+512-512)/128
#define NF    257
#define PADC  256
#define TWO_PI 6.28318530717958647692f
// padded LDS index: +1 float per 32 -> breaks power-of-2 bank aliasing
#define P(i) ((i) + ((i) >> 5))
#define FBUF 528        // padded 512-float FFT region (P(511)=526 < 528)
#define GSTR 264        // staging row stride: 2 rows == FBUF exactly

__device__ __forceinline__ int reflect_idx(int j) {
    j = j < 0 ? -j : j;
    j = j >= LEN ? 2*LEN - 2 - j : j;
    return j;
}

__device__ __forceinline__ float hann(int n) {
    return 0.5f - 0.5f * __cosf(TWO_PI * (float)n * (1.0f / 512.0f));
}

// ---------- sorted-4-smallest tuple machinery (exact, branchless) ----------
struct T4 { float m0, m1, m2, m3; };   // ascending

__device__ __forceinline__ void ins(T4& a, float v) {
    const float x0 = fminf(a.m0, v);  const float c0 = fmaxf(a.m0, v);
    const float x1 = fminf(a.m1, c0); const float c1 = fmaxf(a.m1, c0);
    const float x2 = fminf(a.m2, c1); const float c2 = fmaxf(a.m2, c1);
    const float x3 = fminf(a.m3, c2);
    a.m0 = x0; a.m1 = x1; a.m2 = x2; a.m3 = x3;
}

__device__ __forceinline__ T4 merge4(const T4& a, const T4& b) {
    const float l0 = fminf(a.m0, b.m3);
    const float l1 = fminf(a.m1, b.m2);
    const float l2 = fminf(a.m2, b.m1);
    const float l3 = fminf(a.m3, b.m0);
    const float t0 = fminf(l0, l2), t2 = fmaxf(l0, l2);
    const float t1 = fminf(l1, l3), t3 = fmaxf(l1, l3);
    T4 r;
    r.m0 = fminf(t0, t1); r.m1 = fmaxf(t0, t1);
    r.m2 = fminf(t2, t3); r.m3 = fmaxf(t2, t3);
    return r;
}

__device__ __forceinline__ T4 sort4(float a, float b, float c, float d) {
    const float x0 = fminf(a, b), x1 = fmaxf(a, b);
    const float x2 = fminf(c, d), x3 = fmaxf(c, d);
    const float y0 = fminf(x0, x2), y2 = fmaxf(x0, x2);
    const float y1 = fminf(x1, x3), y3 = fmaxf(x1, x3);
    T4 r; r.m0 = y0; r.m1 = fminf(y1, y2); r.m2 = fmaxf(y1, y2); r.m3 = y3;
    return r;
}

// 8-point DFT in registers. y[m] = sum_r v[r] * exp(sign*2*pi*i*r*m/8).
__device__ __forceinline__ void dft8(float vr[8], float vi[8], float sign) {
    const float K = 0.70710678118654752f;
    float ar=vr[0]+vr[4], ai=vi[0]+vi[4];
    float br=vr[0]-vr[4], bi=vi[0]-vi[4];
    float cr=vr[2]+vr[6], ci=vi[2]+vi[6];
    float dr=vr[2]-vr[6], di=vi[2]-vi[6];
    float er=vr[1]+vr[5], ei=vi[1]+vi[5];
    float fr=vr[1]-vr[5], fi=vi[1]-vi[5];
    float gr=vr[3]+vr[7], gi=vi[3]+vi[7];
    float hr=vr[3]-vr[7], hi=vi[3]-vi[7];
    const float W4dr = -sign*di, W4di = sign*dr;
    const float W4hr = -sign*hi, W4hi = sign*hr;
    const float E0r=ar+cr, E0i=ai+ci, E2r=ar-cr, E2i=ai-ci;
    const float E1r=br+W4dr, E1i=bi+W4di, E3r=br-W4dr, E3i=bi-W4di;
    const float O0r=er+gr, O0i=ei+gi, O2r=er-gr, O2i=ei-gi;
    const float O1r=fr+W4hr, O1i=fi+W4hi, O3r=fr-W4hr, O3i=fi-W4hi;
    const float T1r = K*(O1r - sign*O1i), T1i = K*(O1i + sign*O1r);
    const float T2r = -sign*O2i,          T2i = sign*O2r;
    const float T3r = K*(-O3r - sign*O3i), T3i = K*(-O3i + sign*O3r);
    vr[0]=E0r+O0r; vi[0]=E0i+O0i;  vr[4]=E0r-O0r; vi[4]=E0i-O0i;
    vr[1]=E1r+T1r; vi[1]=E1i+T1i;  vr[5]=E1r-T1r; vi[5]=E1i-T1i;
    vr[2]=E2r+T2r; vi[2]=E2i+T2i;  vr[6]=E2r-T2r; vi[6]=E2i-T2i;
    vr[3]=E3r+T3r; vi[3]=E3i+T3i;  vr[7]=E3r-T3r; vi[7]=E3i-T3i;
}

// One Stockham radix-8 pass, IN PLACE, one wave = one FFT (j in 0..63).
// Barrier-free: all ds_reads precede all ds_writes in program order.
template<int NS>
__device__ __forceinline__ void fft_pass(float* R, float* I, int j, float sign) {
    float vr[8], vi[8];
    #pragma unroll
    for (int r = 0; r < 8; ++r) { vr[r] = R[P(j + 64*r)]; vi[r] = I[P(j + 64*r)]; }
    const float th = sign * (TWO_PI / (8.0f * (float)NS)) * (float)(j & (NS - 1));
    float w1r, w1i; __sincosf(th, &w1i, &w1r);
    float wr = w1r, wi = w1i;
    #pragma unroll
    for (int r = 1; r < 8; ++r) {
        const float tr = vr[r]*wr - vi[r]*wi;
        vi[r] = vr[r]*wi + vi[r]*wr; vr[r] = tr;
        const float nwr = wr*w1r - wi*w1i;
        wi = wr*w1i + wi*w1r; wr = nwr;
    }
    dft8(vr, vi, sign);
    const int base = ((j / NS) * (8 * NS)) + (j & (NS - 1));
    #pragma unroll
    for (int r = 0; r < 8; ++r) { R[P(base + r*NS)] = vr[r]; I[P(base + r*NS)] = vi[r]; }
}

// DUAL Stockham pass: TWO independent in-place FFTs per wave, twiddle
// chain computed ONCE and shared. The second FFT's ops fill the first's
// LDS latency (ILP where occupancy is capped at 4 blocks/CU).
template<int NS>
__device__ __forceinline__ void fft_pass_dual(float* R0, float* I0,
                                              float* R1, float* I1,
                                              int j, float sign) {
    float vr0[8], vi0[8], vr1[8], vi1[8];
    #pragma unroll
    for (int r = 0; r < 8; ++r) {
        vr0[r] = R0[P(j + 64*r)]; vi0[r] = I0[P(j + 64*r)];
        vr1[r] = R1[P(j + 64*r)]; vi1[r] = I1[P(j + 64*r)];
    }
    const float th = sign * (TWO_PI / (8.0f * (float)NS)) * (float)(j & (NS - 1));
    float w1r, w1i; __sincosf(th, &w1i, &w1r);
    float wr = w1r, wi = w1i;
    #pragma unroll
    for (int r = 1; r < 8; ++r) {
        const float t0 = vr0[r]*wr - vi0[r]*wi;
        vi0[r] = vr0[r]*wi + vi0[r]*wr; vr0[r] = t0;
        const float t1 = vr1[r]*wr - vi1[r]*wi;
        vi1[r] = vr1[r]*wi + vi1[r]*wr; vr1[r] = t1;
        const float nwr = wr*w1r - wi*w1i;
        wi = wr*w1i + wi*w1r; wr = nwr;
    }
    dft8(vr0, vi0, sign);
    dft8(vr1, vi1, sign);
    const int base = ((j / NS) * (8 * NS)) + (j & (NS - 1));
    #pragma unroll
    for (int r = 0; r < 8; ++r) {
        R0[P(base + r*NS)] = vr0[r]; I0[P(base + r*NS)] = vi0[r];
        R1[P(base + r*NS)] = vr1[r]; I1[P(base + r*NS)] = vi1[r];
    }
}

// DUAL final pass (NS=64): both results stay in REGISTERS (lane j holds
// y[j+64r]); shared twiddles, no LDS writes.
__device__ __forceinline__ void fft_pass_last_dual(const float* R0, const float* I0,
                                                   const float* R1, const float* I1,
                                                   int j, float sign,
                                                   float vr0[8], float vi0[8],
                                                   float vr1[8], float vi1[8]) {
    #pragma unroll
    for (int r = 0; r < 8; ++r) {
        vr0[r] = R0[P(j + 64*r)]; vi0[r] = I0[P(j + 64*r)];
        vr1[r] = R1[P(j + 64*r)]; vi1[r] = I1[P(j + 64*r)];
    }
    const float th = sign * (TWO_PI / 512.0f) * (float)j;
    float w1r, w1i; __sincosf(th, &w1i, &w1r);
    float wr = w1r, wi = w1i;
    #pragma unroll
    for (int r = 1; r < 8; ++r) {
        const float t0 = vr0[r]*wr - vi0[r]*wi;
        vi0[r] = vr0[r]*wi + vi0[r]*wr; vr0[r] = t0;
        const float t1 = vr1[r]*wr - vi1[r]*wi;
        vi1[r] = vr1[r]*wi + vi1[r]*wr; vr1[r] = t1;
        const float nwr = wr*w1r - wi*w1i;
        wi = wr*w1i + wi*w1r; wr = nwr;
    }
    dft8(vr0, vi0, sign);
    dft8(vr1, vi1, sign);
}

// Final pass (single) — kept for istft_ola.
__device__ __forceinline__ void fft_pass_last(const float* R, const float* I, int j,
                                              float sign, float vr[8], float vi[8]) {
    #pragma unroll
    for (int r = 0; r < 8; ++r) { vr[r] = R[P(j + 64*r)]; vi[r] = I[P(j + 64*r)]; }
    const float th = sign * (TWO_PI / 512.0f) * (float)j;
    float w1r, w1i; __sincosf(th, &w1i, &w1r);
    float wr = w1r, wi = w1i;
    #pragma unroll
    for (int r = 1; r < 8; ++r) {
        const float tr = vr[r]*wr - vi[r]*wi;
        vi[r] = vr[r]*wi + vi[r]*wr; vr[r] = tr;
        const float nwr = wr*w1r - wi*w1i;
        wi = wr*w1i + wi*w1r; wr = nwr;
    }
    dft8(vr, vi, sign);
}

// K1: STFT of BOTH signals via one complex FFT per frame: z = enh + i*noi.
// DUAL-FFT waves: each wave runs TWO adjacent frames' FFTs interleaved
// (8 frames per block), wave-autonomous, in-place, ZERO __syncthreads.
// LDS 33.8 KB -> 4 blocks/CU = exactly the launch-bounds occupancy.
__global__ __launch_bounds__(256, 4) void stft_kernel(const float* __restrict__ enh,
                                                      const float* __restrict__ noi,
                                                      float2* __restrict__ e_spec,
                                                      float*  __restrict__ n_mag) {
    __shared__ float Ar[8*FBUF], Ai[8*FBUF];
    const int tid = threadIdx.x;
    const int w = tid >> 6, j = tid & 63;
    const int b = blockIdx.y;
    const int tp = blockIdx.x * 8 + 2*w;        // this wave's frame pair
    const bool live0 = tp < NT, live1 = tp + 1 < NT;
    const int t0 = live0 ? tp : NT - 1;
    const int t1 = live1 ? tp + 1 : NT - 1;
    float* ar0 = Ar + (2*w)*FBUF;     float* ai0 = Ai + (2*w)*FBUF;
    float* ar1 = Ar + (2*w+1)*FBUF;   float* ai1 = Ai + (2*w+1)*FBUF;

    // pass 0: global -> registers (windowed), dft8 x2, write both regions
    {
        const int s0 = t0 * HOP - PADC;
        const int s1 = t1 * HOP - PADC;
        const float* __restrict__ pe = enh + b * LEN;
        const float* __restrict__ pn = noi + b * LEN;
        float vr0[8], vi0[8], vr1[8], vi1[8];
        if (s0 >= 0 && s1 + NFFT <= LEN) {
            #pragma unroll
            for (int r = 0; r < 8; ++r) {
                const int n = j + 64*r;
                const float wd = hann(n);
                vr0[r] = pe[s0 + n] * wd;  vi0[r] = pn[s0 + n] * wd;
                vr1[r] = pe[s1 + n] * wd;  vi1[r] = pn[s1 + n] * wd;
            }
        } else {
            #pragma unroll
            for (int r = 0; r < 8; ++r) {
                const int n = j + 64*r;
                const float wd = hann(n);
                const int i0 = reflect_idx(s0 + n);
                const int i1 = reflect_idx(s1 + n);
                vr0[r] = pe[i0] * wd;  vi0[r] = pn[i0] * wd;
                vr1[r] = pe[i1] * wd;  vi1[r] = pn[i1] * wd;
            }
        }
        dft8(vr0, vi0, -1.0f);
        dft8(vr1, vi1, -1.0f);
        #pragma unroll
        for (int r = 0; r < 8; ++r) {
            ar0[P(8*j + r)] = vr0[r]; ai0[P(8*j + r)] = vi0[r];
            ar1[P(8*j + r)] = vr1[r]; ai1[P(8*j + r)] = vi1[r];
        }
    }
    fft_pass_dual<8>(ar0, ai0, ar1, ai1, j, -1.0f);
    float zr0[8], zi0[8], zr1[8], zi1[8];
    fft_pass_last_dual(ar0, ai0, ar1, ai1, j, -1.0f, zr0, zi0, zr1, zi1);

    // Hermitian partners via cross-lane shuffle, both FFTs
    const int src = (64 - j) & 63;
    float pr0[4], pi0[4], pr1[4], pi1[4];
    #pragma unroll
    for (int q = 4; q < 8; ++q) {
        pr0[q-4] = __shfl(zr0[q], src);  pi0[q-4] = __shfl(zi0[q], src);
        pr1[q-4] = __shfl(zr1[q], src);  pi1[q-4] = __shfl(zi1[q], src);
    }
    if (live0) {
        const int obase = (b * NT + t0) * NF;
        #pragma unroll
        for (int r = 0; r < 4; ++r) {
            const int kk = j + 64*r;
            const float yr = (j == 0) ? zr0[(8 - r) & 7] : pr0[3 - r];
            const float yi = (j == 0) ? zi0[(8 - r) & 7] : pi0[3 - r];
            const float er = 0.5f*(zr0[r] + yr), ei = 0.5f*(zi0[r] - yi);
            const float nr = 0.5f*(zi0[r] + yi), ni = 0.5f*(yr - zr0[r]);
            e_spec[obase + kk] = make_float2(er, ei);
            n_mag[obase + kk] = fmaxf(sqrtf(nr*nr + ni*ni), 1e-6f);
        }
        if (j == 0) {
            e_spec[obase + 256] = make_float2(zr0[4], 0.0f);
            n_mag[obase + 256] = fmaxf(fabsf(zi0[4]), 1e-6f);
        }
    }
    if (live1) {
        const int obase = (b * NT + t1) * NF;
        #pragma unroll
        for (int r = 0; r < 4; ++r) {
            const int kk = j + 64*r;
            const float yr = (j == 0) ? zr1[(8 - r) & 7] : pr1[3 - r];
            const float yi = (j == 0) ? zi1[(8 - r) & 7] : pi1[3 - r];
            const float er = 0.5f*(zr1[r] + yr), ei = 0.5f*(zi1[r] - yi);
            const float nr = 0.5f*(zi1[r] + yi), ni = 0.5f*(yr - zr1[r]);
            e_spec[obase + kk] = make_float2(er, ei);
            n_mag[obase + kk] = fmaxf(sqrtf(nr*nr + ni*ni), 1e-6f);
        }
        if (j == 0) {
            e_spec[obase + 256] = make_float2(zr1[4], 0.0f);
            n_mag[obase + 256] = fmaxf(fabsf(zi1[4]), 1e-6f);
        }
    }
}

// K2: FULLY fused floor (R10 config). Tile = 16 outputs (24 quantile rows
// incl. +/-4 halo; 54-element time window in registers). Quantile =
// 4th-smallest of 31 via chunked selection. Freq-pool k=5 via LDS;
// time-pool k=9 sliding.
__global__ __launch_bounds__(256) void floor_kernel(const float* __restrict__ n_mag,
                                                    float* __restrict__ floor_) {
    __shared__ float q[24][GSTR];
    __shared__ float fq[24];
    const int tid = threadIdx.x;
    const int t0 = blockIdx.x * 16, b = blockIdx.y;
    const float* __restrict__ pb = n_mag + b * NT * NF;

    // ---- phase A: quantile rows k=0..23 (tq = t0-4+k) for f = tid ----
    {
        float wv[54];
        #pragma unroll
        for (int r = 0; r < 54; ++r) {
            int tr = t0 - 19 + r;
            tr = tr < 0 ? 0 : (tr > NT - 1 ? NT - 1 : tr);
            wv[r] = pb[tr * NF + tid];
        }
        T4 ch[6];
        #pragma unroll
        for (int c = 0; c < 6; ++c)
            ch[c] = merge4(sort4(wv[8*c],   wv[8*c+1], wv[8*c+2], wv[8*c+3]),
                           sort4(wv[8*c+4], wv[8*c+5], wv[8*c+6], wv[8*c+7]));
        #pragma unroll
        for (int k = 0; k < 24; ++k) {
            const int c0 = (k + 7) >> 3;      // full chunks c0, c0+1, c0+2
            T4 m = merge4(merge4(ch[c0], ch[c0+1]), ch[c0+2]);
            #pragma unroll
            for (int jj = k; jj < 8*c0; ++jj) ins(m, wv[jj]);        // head
            #pragma unroll
            for (int jj = 8*c0 + 24; jj < k + 31; ++jj) ins(m, wv[jj]); // tail
            q[k][tid] = m.m3;
        }
    }
    // f = 256 column: threads 0..23, one quantile row each (naive 31-insert)
    if (tid < 24) {
        const int k = tid;
        T4 m; m.m0 = m.m1 = m.m2 = m.m3 = 3.4e38f;
        for (int dt = -15; dt <= 15; ++dt) {
            int tt = t0 - 4 + k + dt;
            tt = tt < 0 ? 0 : (tt > NT - 1 ? NT - 1 : tt);
            ins(m, pb[tt * NF + 256]);
        }
        q[k][256] = m.m3;
    }
    __syncthreads();

    // ---- phase B: freq pool k=5 (zero-pad) into registers ----
    float fp[24];
    {
        const int f = tid;
        #pragma unroll
        for (int k = 0; k < 24; ++k) {
            float acc = 0.0f;
            #pragma unroll
            for (int df = -2; df <= 2; ++df) {
                const int ff = f + df;
                if (ff >= 0 && ff < NF) acc += q[k][ff];
            }
            fp[k] = acc * (1.0f / 5.0f);
        }
    }
    if (tid < 24) {   // f = 256 pooled rows -> fq
        const int k = tid;
        fq[k] = (q[k][254] + q[k][255] + q[k][256]) * (1.0f / 5.0f);
    }
    __syncthreads();

    // ---- phase C: zero out-of-range rows, time pool k=9 sliding, store ----
    {
        const int f = tid;
        #pragma unroll
        for (int k = 0; k < 24; ++k) {
            const int tq = t0 - 4 + k;
            fp[k] = (tq >= 0 && tq < NT) ? fp[k] : 0.0f;
        }
        float acc = 0.0f;
        #pragma unroll
        for (int k = 0; k < 9; ++k) acc += fp[k];
        #pragma unroll
        for (int to = 0; to < 16; ++to) {
            const int t = t0 + to;
            if (t < NT)
                floor_[(b * NT + t) * NF + f] = fmaxf(acc * (1.0f / 9.0f), 1e-6f);
            if (to < 15) acc += fp[to + 9] - fp[to];
        }
    }
    if (tid < 16) {   // f = 256 outputs
        const int to = tid;
        const int t = t0 + to;
        if (t < NT) {
            float acc = 0.0f;
            #pragma unroll
            for (int k = 0; k < 9; ++k) {
                const int tq = t0 - 4 + to + k;
                acc += (tq >= 0 && tq < NT) ? fq[to + k] : 0.0f;
            }
            floor_[(b * NT + t) * NF + 256] = fmaxf(acc * (1.0f / 9.0f), 1e-6f);
        }
    }
}

// K3: fused [mask + ISTFT + OLA] (R10 version). Block computes frames
// t0..t0+7 exactly once, windows into LDS, one barrier, OLA -> out
// (owner store / boundary atomicAdd; out pre-zeroed by hipMemsetAsync).
__global__ __launch_bounds__(256, 4) void istft_ola_kernel(const float2* __restrict__ g,
                                                           const float* __restrict__ floor_,
                                                           float* __restrict__ out) {
    __shared__ float gr[8*GSTR], gi[8*GSTR];
    const int tid = threadIdx.x;
    const int w = tid >> 6, j = tid & 63;
    const int t0 = blockIdx.x * 8, b = blockIdx.y;
    const int ta = t0 + 2*w;

    float* g0r = gr + (2*w) * GSTR;      float* g0i = gi + (2*w) * GSTR;
    float* g1r = gr + (2*w + 1) * GSTR;  float* g1i = gi + (2*w + 1) * GSTR;

    // mask phase (wave-local): fill this wave's 2 staging rows
    for (int e = j; e < 2 * NF; e += 64) {
        const int h = (e >= NF) ? 1 : 0;
        const int kk = e - h * NF;
        const int t = ta + h;
        float grv = 0.0f, giv = 0.0f;
        if (t < NT) {
            const int idx = (b * NT + t) * NF + kk;
            const float fl = floor_[idx];
            const float2 e2 = g[idx];
            const float a = sqrtf(e2.x * e2.x + e2.y * e2.y);
            const float emag = fmaxf(a, 1e-6f);
            const float xarg = (emag - 1.5f * fl) / (0.15f * fl + 1e-6f);
            const float mask = 1.0f / (1.0f + __expf(-xarg));
            const float fm = 0.08f + 0.92f * (0.65f + 0.35f * mask);
            const float scale = emag * fm / fmaxf(a, 1e-12f);
            grv = e2.x * scale; giv = e2.y * scale;
        }
        gr[(2*w + h) * GSTR + kk] = grv;
        gi[(2*w + h) * GSTR + kk] = giv;
    }

    float* ar = g0r;   // FFT region = this wave's two staging rows (528 floats)
    float* ai = g0i;

    // pass 0: build packed C(n) = G1full + i*G2full from staging, dft8,
    // write back into the same region (all reads precede all writes).
    {
        float vr[8], vi[8];
        #pragma unroll
        for (int r = 0; r < 8; ++r) {
            const int n = j + 64*r;
            float cr, ci;
            if (n <= 256) {
                cr = g0r[n] - g1i[n];
                ci = g0i[n] + g1r[n];
            } else {
                const int m = 512 - n;
                cr = g0r[m] + g1i[m];
                ci = g1r[m] - g0i[m];
            }
            vr[r] = cr; vi[r] = ci;
        }
        dft8(vr, vi, 1.0f);
        #pragma unroll
        for (int r = 0; r < 8; ++r) { ar[P(8*j + r)] = vr[r]; ai[P(8*j + r)] = vi[r]; }
    }
    fft_pass<8>(ar, ai, j, 1.0f);
    float xr[8], xi[8];
    fft_pass_last(ar, ai, j, 1.0f, xr, xi);

    // window in place: Re plane = frame ta, Im plane = frame ta+1
    #pragma unroll
    for (int r = 0; r < 8; ++r) {
        const int n = j + 64*r;
        const float wd = hann(n) * (1.0f / 512.0f);
        ar[P(n)] = xr[r] * wd;
        ai[P(n)] = xi[r] * wd;
    }
    __syncthreads();

    // OLA: samples i in [t0*128, t0*128 + 1408) (padded coords)
    const int i0 = t0 << 7;
    for (int s = tid; s < 1408; s += 256) {
        const int i = i0 + s;
        const int jj = i - PADC;
        if (jj < 0 || jj >= LEN) continue;
        const int tl = (i >= 384) ? ((i - 384) >> 7) : 0;
        int th = i >> 7; if (th > NT - 1) th = NT - 1;
        const int ca = tl > t0 ? tl : t0;             // this block's frame range
        const int cb = th < t0 + 7 ? th : t0 + 7;
        if (cb < ca) continue;
        float acc = 0.0f;
        for (int t = ca; t <= cb; ++t) {
            const int ft = t - t0;
            const int n = i - (t << 7);
            acc += ((ft & 1) ? gi : gr)[(ft >> 1) * FBUF + P(n)];
        }
        float winv;
        if (th - tl == 3) winv = (2.0f / 3.0f);       // COLA: sum hann^2 = 1.5
        else {
            float wacc = 0.0f;
            for (int t = tl; t <= th; ++t) {
                const float wd = hann(i - (t << 7));
                wacc += wd * wd;
            }
            winv = 1.0f / fmaxf(wacc, 1e-11f);
        }
        const float v = acc * winv;
        if (tl >= t0 && th <= t0 + 7) out[b * LEN + jj] = v;        // unique owner
        else atomicAdd(out + b * LEN + jj, v);                      // boundary partial
    }
}

extern "C" void kernel_launch(void* const* d_in, const int* in_sizes, int n_in,
                              void* d_out, int out_size, void* d_ws, size_t ws_size,
                              hipStream_t stream) {
    const float* noisy    = (const float*)d_in[0];
    const float* enhanced = (const float*)d_in[1];
    float* out = (float*)d_out;

    // workspace layout (floats), total 20576448 (~82.3 MB):
    //   e_spec : [0, 10288224)              (16*1251*257 float2)
    //   floor  : [10288224, 15432336)
    //   n_mag  : [15432336, 20576448)
    float* ws = (float*)d_ws;
    float2* e_spec = (float2*)ws;
    float* floor_ = ws + 10288224;
    float* n_mag  = ws + 15432336;

    stft_kernel <<<dim3((NT + 7) / 8, BATCH), dim3(256), 0, stream>>>(enhanced, noisy, e_spec, n_mag);
    floor_kernel<<<dim3((NT + 15) / 16, BATCH), dim3(256), 0, stream>>>(n_mag, floor_);
    hipMemsetAsync(out, 0, (size_t)BATCH * LEN * sizeof(float), stream);
    istft_ola_kernel<<<dim3((NT + 7) / 8, BATCH), dim3(256), 0, stream>>>(e_spec, floor_, out);
}

// Round 14
// 141.164 us; speedup vs baseline: 1.0515x; 1.0117x over previous
//
#include <hip/hip_runtime.h>
#include <hip/hip_bf16.h>
#include <math.h>

#define BATCH 16
#define LEN   160000
#define NFFT  512
#define HOP   128
#define NT    1251      // 1 + (160000+512-512)/128
#define NF    257
#define PADC  256
#define TWO_PI 6.28318530717958647692f
// padded LDS index: +1 float per 32 -> breaks power-of-2 bank aliasing
#define P(i) ((i) + ((i) >> 5))
#define FBUF 528        // padded 512-float FFT region (P(511)=526 < 528)
#define GSTR 264        // staging row stride: 2 rows == FBUF exactly

__device__ __forceinline__ int reflect_idx(int j) {
    j = j < 0 ? -j : j;
    j = j >= LEN ? 2*LEN - 2 - j : j;
    return j;
}

__device__ __forceinline__ float hann(int n) {
    return 0.5f - 0.5f * __cosf(TWO_PI * (float)n * (1.0f / 512.0f));
}

__device__ __forceinline__ __hip_bfloat162 pack_bf2(float x, float y) {
    __hip_bfloat162 r; r.x = __float2bfloat16(x); r.y = __float2bfloat16(y); return r;
}
__device__ __forceinline__ float2 unpack_bf2(__hip_bfloat162 v) {
    return make_float2(__bfloat162float(v.x), __bfloat162float(v.y));
}

// ---------- sorted-4-smallest tuple machinery (exact, branchless) ----------
struct T4 { float m0, m1, m2, m3; };   // ascending

__device__ __forceinline__ void ins(T4& a, float v) {
    const float x0 = fminf(a.m0, v);  const float c0 = fmaxf(a.m0, v);
    const float x1 = fminf(a.m1, c0); const float c1 = fmaxf(a.m1, c0);
    const float x2 = fminf(a.m2, c1); const float c2 = fmaxf(a.m2, c1);
    const float x3 = fminf(a.m3, c2);
    a.m0 = x0; a.m1 = x1; a.m2 = x2; a.m3 = x3;
}

__device__ __forceinline__ T4 merge4(const T4& a, const T4& b) {
    const float l0 = fminf(a.m0, b.m3);
    const float l1 = fminf(a.m1, b.m2);
    const float l2 = fminf(a.m2, b.m1);
    const float l3 = fminf(a.m3, b.m0);
    const float t0 = fminf(l0, l2), t2 = fmaxf(l0, l2);
    const float t1 = fminf(l1, l3), t3 = fmaxf(l1, l3);
    T4 r;
    r.m0 = fminf(t0, t1); r.m1 = fmaxf(t0, t1);
    r.m2 = fminf(t2, t3); r.m3 = fmaxf(t2, t3);
    return r;
}

__device__ __forceinline__ T4 sort4(float a, float b, float c, float d) {
    const float x0 = fminf(a, b), x1 = fmaxf(a, b);
    const float x2 = fminf(c, d), x3 = fmaxf(c, d);
    const float y0 = fminf(x0, x2), y2 = fmaxf(x0, x2);
    const float y1 = fminf(x1, x3), y3 = fmaxf(x1, x3);
    T4 r; r.m0 = y0; r.m1 = fminf(y1, y2); r.m2 = fmaxf(y1, y2); r.m3 = y3;
    return r;
}

// 8-point DFT in registers. y[m] = sum_r v[r] * exp(sign*2*pi*i*r*m/8).
__device__ __forceinline__ void dft8(float vr[8], float vi[8], float sign) {
    const float K = 0.70710678118654752f;
    float ar=vr[0]+vr[4], ai=vi[0]+vi[4];
    float br=vr[0]-vr[4], bi=vi[0]-vi[4];
    float cr=vr[2]+vr[6], ci=vi[2]+vi[6];
    float dr=vr[2]-vr[6], di=vi[2]-vi[6];
    float er=vr[1]+vr[5], ei=vi[1]+vi[5];
    float fr=vr[1]-vr[5], fi=vi[1]-vi[5];
    float gr=vr[3]+vr[7], gi=vi[3]+vi[7];
    float hr=vr[3]-vr[7], hi=vi[3]-vi[7];
    const float W4dr = -sign*di, W4di = sign*dr;
    const float W4hr = -sign*hi, W4hi = sign*hr;
    const float E0r=ar+cr, E0i=ai+ci, E2r=ar-cr, E2i=ai-ci;
    const float E1r=br+W4dr, E1i=bi+W4di, E3r=br-W4dr, E3i=bi-W4di;
    const float O0r=er+gr, O0i=ei+gi, O2r=er-gr, O2i=ei-gi;
    const float O1r=fr+W4hr, O1i=fi+W4hi, O3r=fr-W4hr, O3i=fi-W4hi;
    const float T1r = K*(O1r - sign*O1i), T1i = K*(O1i + sign*O1r);
    const float T2r = -sign*O2i,          T2i = sign*O2r;
    const float T3r = K*(-O3r - sign*O3i), T3i = K*(-O3i + sign*O3r);
    vr[0]=E0r+O0r; vi[0]=E0i+O0i;  vr[4]=E0r-O0r; vi[4]=E0i-O0i;
    vr[1]=E1r+T1r; vi[1]=E1i+T1i;  vr[5]=E1r-T1r; vi[5]=E1i-T1i;
    vr[2]=E2r+T2r; vi[2]=E2i+T2i;  vr[6]=E2r-T2r; vi[6]=E2i-T2i;
    vr[3]=E3r+T3r; vi[3]=E3i+T3i;  vr[7]=E3r-T3r; vi[7]=E3i-T3i;
}

// One Stockham radix-8 pass, IN PLACE, one wave = one FFT (j in 0..63).
// Barrier-free: all ds_reads precede all ds_writes in program order.
template<int NS>
__device__ __forceinline__ void fft_pass(float* R, float* I, int j, float sign) {
    float vr[8], vi[8];
    #pragma unroll
    for (int r = 0; r < 8; ++r) { vr[r] = R[P(j + 64*r)]; vi[r] = I[P(j + 64*r)]; }
    const float th = sign * (TWO_PI / (8.0f * (float)NS)) * (float)(j & (NS - 1));
    float w1r, w1i; __sincosf(th, &w1i, &w1r);
    float wr = w1r, wi = w1i;
    #pragma unroll
    for (int r = 1; r < 8; ++r) {
        const float tr = vr[r]*wr - vi[r]*wi;
        vi[r] = vr[r]*wi + vi[r]*wr; vr[r] = tr;
        const float nwr = wr*w1r - wi*w1i;
        wi = wr*w1i + wi*w1r; wr = nwr;
    }
    dft8(vr, vi, sign);
    const int base = ((j / NS) * (8 * NS)) + (j & (NS - 1));
    #pragma unroll
    for (int r = 0; r < 8; ++r) { R[P(base + r*NS)] = vr[r]; I[P(base + r*NS)] = vi[r]; }
}

// Final pass (NS=64): results stay in REGISTERS. After this, lane j holds
// y[j + 64r] in vr[r]/vi[r]. No LDS write.
__device__ __forceinline__ void fft_pass_last(const float* R, const float* I, int j,
                                              float sign, float vr[8], float vi[8]) {
    #pragma unroll
    for (int r = 0; r < 8; ++r) { vr[r] = R[P(j + 64*r)]; vi[r] = I[P(j + 64*r)]; }
    const float th = sign * (TWO_PI / 512.0f) * (float)j;
    float w1r, w1i; __sincosf(th, &w1i, &w1r);
    float wr = w1r, wi = w1i;
    #pragma unroll
    for (int r = 1; r < 8; ++r) {
        const float tr = vr[r]*wr - vi[r]*wi;
        vi[r] = vr[r]*wi + vi[r]*wr; vr[r] = tr;
        const float nwr = wr*w1r - wi*w1i;
        wi = wr*w1i + wi*w1r; wr = nwr;
    }
    dft8(vr, vi, sign);
}

// K1: STFT of BOTH signals via one complex FFT per frame: z = enh + i*noi.
// 4 frames per block (one per wave), wave-autonomous in-place radix-8
// Stockham, ZERO __syncthreads. Last pass in registers; Hermitian partner
// via __shfl. Outputs stored as BF16 (e_spec: bf16x2, n_mag: bf16).
__global__ __launch_bounds__(256, 4) void stft_kernel(const float* __restrict__ enh,
                                                      const float* __restrict__ noi,
                                                      __hip_bfloat162* __restrict__ e_spec,
                                                      __hip_bfloat16*  __restrict__ n_mag) {
    __shared__ float Ar[4*FBUF], Ai[4*FBUF];
    const int tid = threadIdx.x;
    const int w = tid >> 6, j = tid & 63;
    const int tr_ = blockIdx.x * 4 + w;
    const bool live = tr_ < NT;
    const int t = live ? tr_ : NT - 1;
    const int b = blockIdx.y;
    float* ar = Ar + w*FBUF; float* ai = Ai + w*FBUF;

    // pass 0: global -> registers (windowed), dft8, write A
    {
        const int sbase = t * HOP - PADC;
        float vr[8], vi[8];
        if (sbase >= 0 && sbase + NFFT <= LEN) {
            const float* __restrict__ pe = enh + b * LEN + sbase;
            const float* __restrict__ pn = noi + b * LEN + sbase;
            #pragma unroll
            for (int r = 0; r < 8; ++r) {
                const int n = j + 64*r;
                const float wd = hann(n);
                vr[r] = pe[n] * wd;
                vi[r] = pn[n] * wd;
            }
        } else {
            const float* __restrict__ pe = enh + b * LEN;
            const float* __restrict__ pn = noi + b * LEN;
            #pragma unroll
            for (int r = 0; r < 8; ++r) {
                const int n = j + 64*r;
                const int idx = reflect_idx(sbase + n);
                const float wd = hann(n);
                vr[r] = pe[idx] * wd;
                vi[r] = pn[idx] * wd;
            }
        }
        dft8(vr, vi, -1.0f);
        #pragma unroll
        for (int r = 0; r < 8; ++r) { ar[P(8*j + r)] = vr[r]; ai[P(8*j + r)] = vi[r]; }
    }
    fft_pass<8>(ar, ai, j, -1.0f);
    float zr[8], zi[8];
    fft_pass_last(ar, ai, j, -1.0f, zr, zi);

    // Hermitian partner via cross-lane shuffle (regs 4..7 of lane (64-j)&63)
    const int src = (64 - j) & 63;
    float pr[4], pi_[4];
    #pragma unroll
    for (int q = 4; q < 8; ++q) {
        pr[q-4]  = __shfl(zr[q], src);
        pi_[q-4] = __shfl(zi[q], src);
    }
    if (live) {
        const int obase = (b * NT + t) * NF;
        #pragma unroll
        for (int r = 0; r < 4; ++r) {
            const int kk = j + 64*r;
            const float yr = (j == 0) ? zr[(8 - r) & 7] : pr[3 - r];
            const float yi = (j == 0) ? zi[(8 - r) & 7] : pi_[3 - r];
            const float er = 0.5f*(zr[r] + yr), ei = 0.5f*(zi[r] - yi);
            const float nr = 0.5f*(zi[r] + yi), ni = 0.5f*(yr - zr[r]);
            e_spec[obase + kk] = pack_bf2(er, ei);
            n_mag[obase + kk] = __float2bfloat16(fmaxf(sqrtf(nr*nr + ni*ni), 1e-6f));
        }
        if (j == 0) {   // kk = 256: self-conjugate bin
            e_spec[obase + 256] = pack_bf2(zr[4], 0.0f);
            n_mag[obase + 256] = __float2bfloat16(fmaxf(fabsf(zi[4]), 1e-6f));
        }
    }
}

// K2: FULLY fused floor. Tile = 16 outputs (24 quantile rows incl. +/-4
// halo; 54-element time window in registers). Quantile = 4th-smallest of
// 31 via chunked selection. Freq-pool k=5 via LDS; time-pool k=9 sliding.
// Input n_mag is BF16 (half fetch bytes).
__global__ __launch_bounds__(256) void floor_kernel(const __hip_bfloat16* __restrict__ n_mag,
                                                    float* __restrict__ floor_) {
    __shared__ float q[24][GSTR];
    __shared__ float fq[24];
    const int tid = threadIdx.x;
    const int t0 = blockIdx.x * 16, b = blockIdx.y;
    const __hip_bfloat16* __restrict__ pb = n_mag + b * NT * NF;

    // ---- phase A: quantile rows k=0..23 (tq = t0-4+k) for f = tid ----
    {
        float wv[54];
        #pragma unroll
        for (int r = 0; r < 54; ++r) {
            int tr = t0 - 19 + r;
            tr = tr < 0 ? 0 : (tr > NT - 1 ? NT - 1 : tr);
            wv[r] = __bfloat162float(pb[tr * NF + tid]);
        }
        T4 ch[6];
        #pragma unroll
        for (int c = 0; c < 6; ++c)
            ch[c] = merge4(sort4(wv[8*c],   wv[8*c+1], wv[8*c+2], wv[8*c+3]),
                           sort4(wv[8*c+4], wv[8*c+5], wv[8*c+6], wv[8*c+7]));
        #pragma unroll
        for (int k = 0; k < 24; ++k) {
            const int c0 = (k + 7) >> 3;      // full chunks c0, c0+1, c0+2
            T4 m = merge4(merge4(ch[c0], ch[c0+1]), ch[c0+2]);
            #pragma unroll
            for (int jj = k; jj < 8*c0; ++jj) ins(m, wv[jj]);        // head
            #pragma unroll
            for (int jj = 8*c0 + 24; jj < k + 31; ++jj) ins(m, wv[jj]); // tail
            q[k][tid] = m.m3;
        }
    }
    // f = 256 column: threads 0..23, one quantile row each (naive 31-insert)
    if (tid < 24) {
        const int k = tid;
        T4 m; m.m0 = m.m1 = m.m2 = m.m3 = 3.4e38f;
        for (int dt = -15; dt <= 15; ++dt) {
            int tt = t0 - 4 + k + dt;
            tt = tt < 0 ? 0 : (tt > NT - 1 ? NT - 1 : tt);
            ins(m, __bfloat162float(pb[tt * NF + 256]));
        }
        q[k][256] = m.m3;
    }
    __syncthreads();

    // ---- phase B: freq pool k=5 (zero-pad) into registers ----
    float fp[24];
    {
        const int f = tid;
        #pragma unroll
        for (int k = 0; k < 24; ++k) {
            float acc = 0.0f;
            #pragma unroll
            for (int df = -2; df <= 2; ++df) {
                const int ff = f + df;
                if (ff >= 0 && ff < NF) acc += q[k][ff];
            }
            fp[k] = acc * (1.0f / 5.0f);
        }
    }
    if (tid < 24) {   // f = 256 pooled rows -> fq
        const int k = tid;
        fq[k] = (q[k][254] + q[k][255] + q[k][256]) * (1.0f / 5.0f);
    }
    __syncthreads();

    // ---- phase C: zero out-of-range rows, time pool k=9 sliding, store ----
    {
        const int f = tid;
        #pragma unroll
        for (int k = 0; k < 24; ++k) {
            const int tq = t0 - 4 + k;
            fp[k] = (tq >= 0 && tq < NT) ? fp[k] : 0.0f;
        }
        float acc = 0.0f;
        #pragma unroll
        for (int k = 0; k < 9; ++k) acc += fp[k];
        #pragma unroll
        for (int to = 0; to < 16; ++to) {
            const int t = t0 + to;
            if (t < NT)
                floor_[(b * NT + t) * NF + f] = fmaxf(acc * (1.0f / 9.0f), 1e-6f);
            if (to < 15) acc += fp[to + 9] - fp[to];
        }
    }
    if (tid < 16) {   // f = 256 outputs
        const int to = tid;
        const int t = t0 + to;
        if (t < NT) {
            float acc = 0.0f;
            #pragma unroll
            for (int k = 0; k < 9; ++k) {
                const int tq = t0 - 4 + to + k;
                acc += (tq >= 0 && tq < NT) ? fq[to + k] : 0.0f;
            }
            floor_[(b * NT + t) * NF + 256] = fmaxf(acc * (1.0f / 9.0f), 1e-6f);
        }
    }
}

// K3: fused [mask + ISTFT + OLA]. Block computes frames t0..t0+7 exactly
// once, windows into LDS, one barrier, OLA -> out (owner store / boundary
// atomicAdd; out pre-zeroed by hipMemsetAsync). e_spec input is BF16x2.
__global__ __launch_bounds__(256, 4) void istft_ola_kernel(const __hip_bfloat162* __restrict__ g,
                                                           const float* __restrict__ floor_,
                                                           float* __restrict__ out) {
    __shared__ float gr[8*GSTR], gi[8*GSTR];
    const int tid = threadIdx.x;
    const int w = tid >> 6, j = tid & 63;
    const int t0 = blockIdx.x * 8, b = blockIdx.y;
    const int ta = t0 + 2*w;

    float* g0r = gr + (2*w) * GSTR;      float* g0i = gi + (2*w) * GSTR;
    float* g1r = gr + (2*w + 1) * GSTR;  float* g1i = gi + (2*w + 1) * GSTR;

    // mask phase (wave-local): fill this wave's 2 staging rows
    for (int e = j; e < 2 * NF; e += 64) {
        const int h = (e >= NF) ? 1 : 0;
        const int kk = e - h * NF;
        const int t = ta + h;
        float grv = 0.0f, giv = 0.0f;
        if (t < NT) {
            const int idx = (b * NT + t) * NF + kk;
            const float fl = floor_[idx];
            const float2 e2 = unpack_bf2(g[idx]);
            const float a = sqrtf(e2.x * e2.x + e2.y * e2.y);
            const float emag = fmaxf(a, 1e-6f);
            const float xarg = (emag - 1.5f * fl) / (0.15f * fl + 1e-6f);
            const float mask = 1.0f / (1.0f + __expf(-xarg));
            const float fm = 0.08f + 0.92f * (0.65f + 0.35f * mask);
            const float scale = emag * fm / fmaxf(a, 1e-12f);
            grv = e2.x * scale; giv = e2.y * scale;
        }
        gr[(2*w + h) * GSTR + kk] = grv;
        gi[(2*w + h) * GSTR + kk] = giv;
    }

    float* ar = g0r;   // FFT region = this wave's two staging rows (528 floats)
    float* ai = g0i;

    // pass 0: build packed C(n) = G1full + i*G2full from staging, dft8,
    // write back into the same region (all reads precede all writes).
    {
        float vr[8], vi[8];
        #pragma unroll
        for (int r = 0; r < 8; ++r) {
            const int n = j + 64*r;
            float cr, ci;
            if (n <= 256) {
                cr = g0r[n] - g1i[n];
                ci = g0i[n] + g1r[n];
            } else {
                const int m = 512 - n;
                cr = g0r[m] + g1i[m];
                ci = g1r[m] - g0i[m];
            }
            vr[r] = cr; vi[r] = ci;
        }
        dft8(vr, vi, 1.0f);
        #pragma unroll
        for (int r = 0; r < 8; ++r) { ar[P(8*j + r)] = vr[r]; ai[P(8*j + r)] = vi[r]; }
    }
    fft_pass<8>(ar, ai, j, 1.0f);
    float xr[8], xi[8];
    fft_pass_last(ar, ai, j, 1.0f, xr, xi);

    // window in place: Re plane = frame ta, Im plane = frame ta+1
    #pragma unroll
    for (int r = 0; r < 8; ++r) {
        const int n = j + 64*r;
        const float wd = hann(n) * (1.0f / 512.0f);
        ar[P(n)] = xr[r] * wd;
        ai[P(n)] = xi[r] * wd;
    }
    __syncthreads();

    // OLA: samples i in [t0*128, t0*128 + 1408) (padded coords)
    const int i0 = t0 << 7;
    for (int s = tid; s < 1408; s += 256) {
        const int i = i0 + s;
        const int jj = i - PADC;
        if (jj < 0 || jj >= LEN) continue;
        const int tl = (i >= 384) ? ((i - 384) >> 7) : 0;
        int th = i >> 7; if (th > NT - 1) th = NT - 1;
        const int ca = tl > t0 ? tl : t0;             // this block's frame range
        const int cb = th < t0 + 7 ? th : t0 + 7;
        if (cb < ca) continue;
        float acc = 0.0f;
        for (int t = ca; t <= cb; ++t) {
            const int ft = t - t0;
            const int n = i - (t << 7);
            acc += ((ft & 1) ? gi : gr)[(ft >> 1) * FBUF + P(n)];
        }
        float winv;
        if (th - tl == 3) winv = (2.0f / 3.0f);       // COLA: sum hann^2 = 1.5
        else {
            float wacc = 0.0f;
            for (int t = tl; t <= th; ++t) {
                const float wd = hann(i - (t << 7));
                wacc += wd * wd;
            }
            winv = 1.0f / fmaxf(wacc, 1e-11f);
        }
        const float v = acc * winv;
        if (tl >= t0 && th <= t0 + 7) out[b * LEN + jj] = v;        // unique owner
        else atomicAdd(out + b * LEN + jj, v);                      // boundary partial
    }
}

extern "C" void kernel_launch(void* const* d_in, const int* in_sizes, int n_in,
                              void* d_out, int out_size, void* d_ws, size_t ws_size,
                              hipStream_t stream) {
    const float* noisy    = (const float*)d_in[0];
    const float* enhanced = (const float*)d_in[1];
    float* out = (float*)d_out;

    // workspace layout (float offsets), total ~51 MB:
    //   e_spec : [0, 5144112)               (16*1251*257 bf16x2 = 4B each)
    //   floor  : [5144112, 10288224)        (fp32)
    //   n_mag  : [10288224, 11574252)       (bf16, 2B each)
    float* ws = (float*)d_ws;
    __hip_bfloat162* e_spec = (__hip_bfloat162*)ws;
    float* floor_ = ws + 5144112;
    __hip_bfloat16* n_mag = (__hip_bfloat16*)(ws + 10288224);

    stft_kernel <<<dim3((NT + 3) / 4, BATCH), dim3(256), 0, stream>>>(enhanced, noisy, e_spec, n_mag);
    floor_kernel<<<dim3((NT + 15) / 16, BATCH), dim3(256), 0, stream>>>(n_mag, floor_);
    hipMemsetAsync(out, 0, (size_t)BATCH * LEN * sizeof(float), stream);
    istft_ola_kernel<<<dim3((NT + 7) / 8, BATCH), dim3(256), 0, stream>>>(e_spec, floor_, out);
}

// Round 15
// 140.531 us; speedup vs baseline: 1.0563x; 1.0045x over previous
//
#include <hip/hip_runtime.h>
#include <hip/hip_bf16.h>
#include <math.h>

#define BATCH 16
#define LEN   160000
#define NFFT  512
#define HOP   128
#define NT    1251      // 1 + (160000+512-512)/128
#define NF    257
#define PADC  256
#define TWO_PI 6.28318530717958647692f
// padded LDS index: +1 float per 32 -> breaks power-of-2 bank aliasing
#define P(i) ((i) + ((i) >> 5))
#define FBUF 528        // padded 512-float FFT region (P(511)=526 < 528)
#define GSTR 264        // staging row stride: 2 rows == FBUF exactly

__device__ __forceinline__ int reflect_idx(int j) {
    j = j < 0 ? -j : j;
    j = j >= LEN ? 2*LEN - 2 - j : j;
    return j;
}

__device__ __forceinline__ float hann(int n) {
    return 0.5f - 0.5f * __cosf(TWO_PI * (float)n * (1.0f / 512.0f));
}

__device__ __forceinline__ __hip_bfloat162 pack_bf2(float x, float y) {
    __hip_bfloat162 r; r.x = __float2bfloat16(x); r.y = __float2bfloat16(y); return r;
}
__device__ __forceinline__ float2 unpack_bf2(__hip_bfloat162 v) {
    return make_float2(__bfloat162float(v.x), __bfloat162float(v.y));
}

// ---------- sorted-4-smallest tuple machinery (exact, branchless) ----------
struct T4 { float m0, m1, m2, m3; };   // ascending

__device__ __forceinline__ void ins(T4& a, float v) {
    const float x0 = fminf(a.m0, v);  const float c0 = fmaxf(a.m0, v);
    const float x1 = fminf(a.m1, c0); const float c1 = fmaxf(a.m1, c0);
    const float x2 = fminf(a.m2, c1); const float c2 = fmaxf(a.m2, c1);
    const float x3 = fminf(a.m3, c2);
    a.m0 = x0; a.m1 = x1; a.m2 = x2; a.m3 = x3;
}

__device__ __forceinline__ T4 merge4(const T4& a, const T4& b) {
    const float l0 = fminf(a.m0, b.m3);
    const float l1 = fminf(a.m1, b.m2);
    const float l2 = fminf(a.m2, b.m1);
    const float l3 = fminf(a.m3, b.m0);
    const float t0 = fminf(l0, l2), t2 = fmaxf(l0, l2);
    const float t1 = fminf(l1, l3), t3 = fmaxf(l1, l3);
    T4 r;
    r.m0 = fminf(t0, t1); r.m1 = fmaxf(t0, t1);
    r.m2 = fminf(t2, t3); r.m3 = fmaxf(t2, t3);
    return r;
}

__device__ __forceinline__ T4 sort4(float a, float b, float c, float d) {
    const float x0 = fminf(a, b), x1 = fmaxf(a, b);
    const float x2 = fminf(c, d), x3 = fmaxf(c, d);
    const float y0 = fminf(x0, x2), y2 = fmaxf(x0, x2);
    const float y1 = fminf(x1, x3), y3 = fmaxf(x1, x3);
    T4 r; r.m0 = y0; r.m1 = fminf(y1, y2); r.m2 = fmaxf(y1, y2); r.m3 = y3;
    return r;
}

// 8-point DFT in registers. y[m] = sum_r v[r] * exp(sign*2*pi*i*r*m/8).
__device__ __forceinline__ void dft8(float vr[8], float vi[8], float sign) {
    const float K = 0.70710678118654752f;
    float ar=vr[0]+vr[4], ai=vi[0]+vi[4];
    float br=vr[0]-vr[4], bi=vi[0]-vi[4];
    float cr=vr[2]+vr[6], ci=vi[2]+vi[6];
    float dr=vr[2]-vr[6], di=vi[2]-vi[6];
    float er=vr[1]+vr[5], ei=vi[1]+vi[5];
    float fr=vr[1]-vr[5], fi=vi[1]-vi[5];
    float gr=vr[3]+vr[7], gi=vi[3]+vi[7];
    float hr=vr[3]-vr[7], hi=vi[3]-vi[7];
    const float W4dr = -sign*di, W4di = sign*dr;
    const float W4hr = -sign*hi, W4hi = sign*hr;
    const float E0r=ar+cr, E0i=ai+ci, E2r=ar-cr, E2i=ai-ci;
    const float E1r=br+W4dr, E1i=bi+W4di, E3r=br-W4dr, E3i=bi-W4di;
    const float O0r=er+gr, O0i=ei+gi, O2r=er-gr, O2i=ei-gi;
    const float O1r=fr+W4hr, O1i=fi+W4hi, O3r=fr-W4hr, O3i=fi-W4hi;
    const float T1r = K*(O1r - sign*O1i), T1i = K*(O1i + sign*O1r);
    const float T2r = -sign*O2i,          T2i = sign*O2r;
    const float T3r = K*(-O3r - sign*O3i), T3i = K*(-O3i + sign*O3r);
    vr[0]=E0r+O0r; vi[0]=E0i+O0i;  vr[4]=E0r-O0r; vi[4]=E0i-O0i;
    vr[1]=E1r+T1r; vi[1]=E1i+T1i;  vr[5]=E1r-T1r; vi[5]=E1i-T1i;
    vr[2]=E2r+T2r; vi[2]=E2i+T2i;  vr[6]=E2r-T2r; vi[6]=E2i-T2i;
    vr[3]=E3r+T3r; vi[3]=E3i+T3i;  vr[7]=E3r-T3r; vi[7]=E3i-T3i;
}

// One Stockham radix-8 pass, IN PLACE, one wave = one FFT (j in 0..63).
// Barrier-free: all ds_reads precede all ds_writes in program order.
template<int NS>
__device__ __forceinline__ void fft_pass(float* R, float* I, int j, float sign) {
    float vr[8], vi[8];
    #pragma unroll
    for (int r = 0; r < 8; ++r) { vr[r] = R[P(j + 64*r)]; vi[r] = I[P(j + 64*r)]; }
    const float th = sign * (TWO_PI / (8.0f * (float)NS)) * (float)(j & (NS - 1));
    float w1r, w1i; __sincosf(th, &w1i, &w1r);
    float wr = w1r, wi = w1i;
    #pragma unroll
    for (int r = 1; r < 8; ++r) {
        const float tr = vr[r]*wr - vi[r]*wi;
        vi[r] = vr[r]*wi + vi[r]*wr; vr[r] = tr;
        const float nwr = wr*w1r - wi*w1i;
        wi = wr*w1i + wi*w1r; wr = nwr;
    }
    dft8(vr, vi, sign);
    const int base = ((j / NS) * (8 * NS)) + (j & (NS - 1));
    #pragma unroll
    for (int r = 0; r < 8; ++r) { R[P(base + r*NS)] = vr[r]; I[P(base + r*NS)] = vi[r]; }
}

// Final pass (NS=64): results stay in REGISTERS. After this, lane j holds
// y[j + 64r] in vr[r]/vi[r]. No LDS write.
__device__ __forceinline__ void fft_pass_last(const float* R, const float* I, int j,
                                              float sign, float vr[8], float vi[8]) {
    #pragma unroll
    for (int r = 0; r < 8; ++r) { vr[r] = R[P(j + 64*r)]; vi[r] = I[P(j + 64*r)]; }
    const float th = sign * (TWO_PI / 512.0f) * (float)j;
    float w1r, w1i; __sincosf(th, &w1i, &w1r);
    float wr = w1r, wi = w1i;
    #pragma unroll
    for (int r = 1; r < 8; ++r) {
        const float tr = vr[r]*wr - vi[r]*wi;
        vi[r] = vr[r]*wi + vi[r]*wr; vr[r] = tr;
        const float nwr = wr*w1r - wi*w1i;
        wi = wr*w1i + wi*w1r; wr = nwr;
    }
    dft8(vr, vi, sign);
}

// K1: STFT of BOTH signals via one complex FFT per frame: z = enh + i*noi.
// 4 frames per block (one per wave), wave-autonomous in-place radix-8
// Stockham, ZERO __syncthreads. Last pass in registers; Hermitian partner
// via __shfl. Outputs stored as BF16. (256,6): 6 blocks/CU (LDS 16.9 KB
// allows 9; VGPR cap 85 > ~64 needed) — isolated occupancy experiment.
__global__ __launch_bounds__(256, 6) void stft_kernel(const float* __restrict__ enh,
                                                      const float* __restrict__ noi,
                                                      __hip_bfloat162* __restrict__ e_spec,
                                                      __hip_bfloat16*  __restrict__ n_mag) {
    __shared__ float Ar[4*FBUF], Ai[4*FBUF];
    const int tid = threadIdx.x;
    const int w = tid >> 6, j = tid & 63;
    const int tr_ = blockIdx.x * 4 + w;
    const bool live = tr_ < NT;
    const int t = live ? tr_ : NT - 1;
    const int b = blockIdx.y;
    float* ar = Ar + w*FBUF; float* ai = Ai + w*FBUF;

    // pass 0: global -> registers (windowed), dft8, write A
    {
        const int sbase = t * HOP - PADC;
        float vr[8], vi[8];
        if (sbase >= 0 && sbase + NFFT <= LEN) {
            const float* __restrict__ pe = enh + b * LEN + sbase;
            const float* __restrict__ pn = noi + b * LEN + sbase;
            #pragma unroll
            for (int r = 0; r < 8; ++r) {
                const int n = j + 64*r;
                const float wd = hann(n);
                vr[r] = pe[n] * wd;
                vi[r] = pn[n] * wd;
            }
        } else {
            const float* __restrict__ pe = enh + b * LEN;
            const float* __restrict__ pn = noi + b * LEN;
            #pragma unroll
            for (int r = 0; r < 8; ++r) {
                const int n = j + 64*r;
                const int idx = reflect_idx(sbase + n);
                const float wd = hann(n);
                vr[r] = pe[idx] * wd;
                vi[r] = pn[idx] * wd;
            }
        }
        dft8(vr, vi, -1.0f);
        #pragma unroll
        for (int r = 0; r < 8; ++r) { ar[P(8*j + r)] = vr[r]; ai[P(8*j + r)] = vi[r]; }
    }
    fft_pass<8>(ar, ai, j, -1.0f);
    float zr[8], zi[8];
    fft_pass_last(ar, ai, j, -1.0f, zr, zi);

    // Hermitian partner via cross-lane shuffle (regs 4..7 of lane (64-j)&63)
    const int src = (64 - j) & 63;
    float pr[4], pi_[4];
    #pragma unroll
    for (int q = 4; q < 8; ++q) {
        pr[q-4]  = __shfl(zr[q], src);
        pi_[q-4] = __shfl(zi[q], src);
    }
    if (live) {
        const int obase = (b * NT + t) * NF;
        #pragma unroll
        for (int r = 0; r < 4; ++r) {
            const int kk = j + 64*r;
            const float yr = (j == 0) ? zr[(8 - r) & 7] : pr[3 - r];
            const float yi = (j == 0) ? zi[(8 - r) & 7] : pi_[3 - r];
            const float er = 0.5f*(zr[r] + yr), ei = 0.5f*(zi[r] - yi);
            const float nr = 0.5f*(zi[r] + yi), ni = 0.5f*(yr - zr[r]);
            e_spec[obase + kk] = pack_bf2(er, ei);
            n_mag[obase + kk] = __float2bfloat16(fmaxf(sqrtf(nr*nr + ni*ni), 1e-6f));
        }
        if (j == 0) {   // kk = 256: self-conjugate bin
            e_spec[obase + 256] = pack_bf2(zr[4], 0.0f);
            n_mag[obase + 256] = __float2bfloat16(fmaxf(fabsf(zi[4]), 1e-6f));
        }
    }
}

// K2: FULLY fused floor. Tile = 16 outputs (24 quantile rows incl. +/-4
// halo; 54-element time window in registers). Quantile = 4th-smallest of
// 31 via chunked selection. Freq-pool k=5 via LDS; time-pool k=9 sliding.
// Input n_mag is BF16 (half fetch bytes).
__global__ __launch_bounds__(256) void floor_kernel(const __hip_bfloat16* __restrict__ n_mag,
                                                    float* __restrict__ floor_) {
    __shared__ float q[24][GSTR];
    __shared__ float fq[24];
    const int tid = threadIdx.x;
    const int t0 = blockIdx.x * 16, b = blockIdx.y;
    const __hip_bfloat16* __restrict__ pb = n_mag + b * NT * NF;

    // ---- phase A: quantile rows k=0..23 (tq = t0-4+k) for f = tid ----
    {
        float wv[54];
        #pragma unroll
        for (int r = 0; r < 54; ++r) {
            int tr = t0 - 19 + r;
            tr = tr < 0 ? 0 : (tr > NT - 1 ? NT - 1 : tr);
            wv[r] = __bfloat162float(pb[tr * NF + tid]);
        }
        T4 ch[6];
        #pragma unroll
        for (int c = 0; c < 6; ++c)
            ch[c] = merge4(sort4(wv[8*c],   wv[8*c+1], wv[8*c+2], wv[8*c+3]),
                           sort4(wv[8*c+4], wv[8*c+5], wv[8*c+6], wv[8*c+7]));
        #pragma unroll
        for (int k = 0; k < 24; ++k) {
            const int c0 = (k + 7) >> 3;      // full chunks c0, c0+1, c0+2
            T4 m = merge4(merge4(ch[c0], ch[c0+1]), ch[c0+2]);
            #pragma unroll
            for (int jj = k; jj < 8*c0; ++jj) ins(m, wv[jj]);        // head
            #pragma unroll
            for (int jj = 8*c0 + 24; jj < k + 31; ++jj) ins(m, wv[jj]); // tail
            q[k][tid] = m.m3;
        }
    }
    // f = 256 column: threads 0..23, one quantile row each (naive 31-insert)
    if (tid < 24) {
        const int k = tid;
        T4 m; m.m0 = m.m1 = m.m2 = m.m3 = 3.4e38f;
        for (int dt = -15; dt <= 15; ++dt) {
            int tt = t0 - 4 + k + dt;
            tt = tt < 0 ? 0 : (tt > NT - 1 ? NT - 1 : tt);
            ins(m, __bfloat162float(pb[tt * NF + 256]));
        }
        q[k][256] = m.m3;
    }
    __syncthreads();

    // ---- phase B: freq pool k=5 (zero-pad) into registers ----
    float fp[24];
    {
        const int f = tid;
        #pragma unroll
        for (int k = 0; k < 24; ++k) {
            float acc = 0.0f;
            #pragma unroll
            for (int df = -2; df <= 2; ++df) {
                const int ff = f + df;
                if (ff >= 0 && ff < NF) acc += q[k][ff];
            }
            fp[k] = acc * (1.0f / 5.0f);
        }
    }
    if (tid < 24) {   // f = 256 pooled rows -> fq
        const int k = tid;
        fq[k] = (q[k][254] + q[k][255] + q[k][256]) * (1.0f / 5.0f);
    }
    __syncthreads();

    // ---- phase C: zero out-of-range rows, time pool k=9 sliding, store ----
    {
        const int f = tid;
        #pragma unroll
        for (int k = 0; k < 24; ++k) {
            const int tq = t0 - 4 + k;
            fp[k] = (tq >= 0 && tq < NT) ? fp[k] : 0.0f;
        }
        float acc = 0.0f;
        #pragma unroll
        for (int k = 0; k < 9; ++k) acc += fp[k];
        #pragma unroll
        for (int to = 0; to < 16; ++to) {
            const int t = t0 + to;
            if (t < NT)
                floor_[(b * NT + t) * NF + f] = fmaxf(acc * (1.0f / 9.0f), 1e-6f);
            if (to < 15) acc += fp[to + 9] - fp[to];
        }
    }
    if (tid < 16) {   // f = 256 outputs
        const int to = tid;
        const int t = t0 + to;
        if (t < NT) {
            float acc = 0.0f;
            #pragma unroll
            for (int k = 0; k < 9; ++k) {
                const int tq = t0 - 4 + to + k;
                acc += (tq >= 0 && tq < NT) ? fq[to + k] : 0.0f;
            }
            floor_[(b * NT + t) * NF + 256] = fmaxf(acc * (1.0f / 9.0f), 1e-6f);
        }
    }
}

// K3: fused [mask + ISTFT + OLA]. Block computes frames t0..t0+7 exactly
// once, windows into LDS, one barrier, OLA -> out (owner store / boundary
// atomicAdd; out pre-zeroed by hipMemsetAsync). e_spec input is BF16x2.
// (256,6): occupancy experiment, LDS 16.9 KB allows it.
__global__ __launch_bounds__(256, 6) void istft_ola_kernel(const __hip_bfloat162* __restrict__ g,
                                                           const float* __restrict__ floor_,
                                                           float* __restrict__ out) {
    __shared__ float gr[8*GSTR], gi[8*GSTR];
    const int tid = threadIdx.x;
    const int w = tid >> 6, j = tid & 63;
    const int t0 = blockIdx.x * 8, b = blockIdx.y;
    const int ta = t0 + 2*w;

    float* g0r = gr + (2*w) * GSTR;      float* g0i = gi + (2*w) * GSTR;
    float* g1r = gr + (2*w + 1) * GSTR;  float* g1i = gi + (2*w + 1) * GSTR;

    // mask phase (wave-local): fill this wave's 2 staging rows
    for (int e = j; e < 2 * NF; e += 64) {
        const int h = (e >= NF) ? 1 : 0;
        const int kk = e - h * NF;
        const int t = ta + h;
        float grv = 0.0f, giv = 0.0f;
        if (t < NT) {
            const int idx = (b * NT + t) * NF + kk;
            const float fl = floor_[idx];
            const float2 e2 = unpack_bf2(g[idx]);
            const float a = sqrtf(e2.x * e2.x + e2.y * e2.y);
            const float emag = fmaxf(a, 1e-6f);
            const float xarg = (emag - 1.5f * fl) / (0.15f * fl + 1e-6f);
            const float mask = 1.0f / (1.0f + __expf(-xarg));
            const float fm = 0.08f + 0.92f * (0.65f + 0.35f * mask);
            const float scale = emag * fm / fmaxf(a, 1e-12f);
            grv = e2.x * scale; giv = e2.y * scale;
        }
        gr[(2*w + h) * GSTR + kk] = grv;
        gi[(2*w + h) * GSTR + kk] = giv;
    }

    float* ar = g0r;   // FFT region = this wave's two staging rows (528 floats)
    float* ai = g0i;

    // pass 0: build packed C(n) = G1full + i*G2full from staging, dft8,
    // write back into the same region (all reads precede all writes).
    {
        float vr[8], vi[8];
        #pragma unroll
        for (int r = 0; r < 8; ++r) {
            const int n = j + 64*r;
            float cr, ci;
            if (n <= 256) {
                cr = g0r[n] - g1i[n];
                ci = g0i[n] + g1r[n];
            } else {
                const int m = 512 - n;
                cr = g0r[m] + g1i[m];
                ci = g1r[m] - g0i[m];
            }
            vr[r] = cr; vi[r] = ci;
        }
        dft8(vr, vi, 1.0f);
        #pragma unroll
        for (int r = 0; r < 8; ++r) { ar[P(8*j + r)] = vr[r]; ai[P(8*j + r)] = vi[r]; }
    }
    fft_pass<8>(ar, ai, j, 1.0f);
    float xr[8], xi[8];
    fft_pass_last(ar, ai, j, 1.0f, xr, xi);

    // window in place: Re plane = frame ta, Im plane = frame ta+1
    #pragma unroll
    for (int r = 0; r < 8; ++r) {
        const int n = j + 64*r;
        const float wd = hann(n) * (1.0f / 512.0f);
        ar[P(n)] = xr[r] * wd;
        ai[P(n)] = xi[r] * wd;
    }
    __syncthreads();

    // OLA: samples i in [t0*128, t0*128 + 1408) (padded coords)
    const int i0 = t0 << 7;
    for (int s = tid; s < 1408; s += 256) {
        const int i = i0 + s;
        const int jj = i - PADC;
        if (jj < 0 || jj >= LEN) continue;
        const int tl = (i >= 384) ? ((i - 384) >> 7) : 0;
        int th = i >> 7; if (th > NT - 1) th = NT - 1;
        const int ca = tl > t0 ? tl : t0;             // this block's frame range
        const int cb = th < t0 + 7 ? th : t0 + 7;
        if (cb < ca) continue;
        float acc = 0.0f;
        for (int t = ca; t <= cb; ++t) {
            const int ft = t - t0;
            const int n = i - (t << 7);
            acc += ((ft & 1) ? gi : gr)[(ft >> 1) * FBUF + P(n)];
        }
        float winv;
        if (th - tl == 3) winv = (2.0f / 3.0f);       // COLA: sum hann^2 = 1.5
        else {
            float wacc = 0.0f;
            for (int t = tl; t <= th; ++t) {
                const float wd = hann(i - (t << 7));
                wacc += wd * wd;
            }
            winv = 1.0f / fmaxf(wacc, 1e-11f);
        }
        const float v = acc * winv;
        if (tl >= t0 && th <= t0 + 7) out[b * LEN + jj] = v;        // unique owner
        else atomicAdd(out + b * LEN + jj, v);                      // boundary partial
    }
}

extern "C" void kernel_launch(void* const* d_in, const int* in_sizes, int n_in,
                              void* d_out, int out_size, void* d_ws, size_t ws_size,
                              hipStream_t stream) {
    const float* noisy    = (const float*)d_in[0];
    const float* enhanced = (const float*)d_in[1];
    float* out = (float*)d_out;

    // workspace layout (float offsets), total ~51 MB:
    //   e_spec : [0, 5144112)               (16*1251*257 bf16x2 = 4B each)
    //   floor  : [5144112, 10288224)        (fp32)
    //   n_mag  : [10288224, 11574252)       (bf16, 2B each)
    float* ws = (float*)d_ws;
    __hip_bfloat162* e_spec = (__hip_bfloat162*)ws;
    float* floor_ = ws + 5144112;
    __hip_bfloat16* n_mag = (__hip_bfloat16*)(ws + 10288224);

    stft_kernel <<<dim3((NT + 3) / 4, BATCH), dim3(256), 0, stream>>>(enhanced, noisy, e_spec, n_mag);
    floor_kernel<<<dim3((NT + 15) / 16, BATCH), dim3(256), 0, stream>>>(n_mag, floor_);
    hipMemsetAsync(out, 0, (size_t)BATCH * LEN * sizeof(float), stream);
    istft_ola_kernel<<<dim3((NT + 7) / 8, BATCH), dim3(256), 0, stream>>>(e_spec, floor_, out);
}